// Round 1
// 1270.163 us; speedup vs baseline: 1.1031x; 1.1031x over previous
//
#include <hip/hip_runtime.h>
#include <math.h>

#define NN 4096
#define EE 65536
#define H 128
#define NF 4
#define MNODE 8
#define MEDGE 4
#define NT 2

// ---------------- CSR build ----------------
__global__ void k_count(const int* __restrict__ dst, int* __restrict__ cnt) {
  int e = blockIdx.x * 256 + threadIdx.x;
  if (e < EE) atomicAdd(&cnt[dst[e]], 1);
}

__global__ void k_scan(const int* __restrict__ cnt, int* __restrict__ rp) {
  __shared__ int sh[1024];
  int t = threadIdx.x;
  int v0 = cnt[4*t], v1 = cnt[4*t+1], v2 = cnt[4*t+2], v3 = cnt[4*t+3];
  int p1 = v0, p2 = v0 + v1, p3 = p2 + v2, tot = p3 + v3;
  sh[t] = tot; __syncthreads();
  for (int off = 1; off < 1024; off <<= 1) {
    int add = (t >= off) ? sh[t-off] : 0;
    __syncthreads();
    sh[t] += add;
    __syncthreads();
  }
  int base = sh[t] - tot;
  rp[4*t] = base; rp[4*t+1] = base + p1; rp[4*t+2] = base + p2; rp[4*t+3] = base + p3;
  if (t == 1023) rp[NN] = sh[t];
}

__global__ void k_fill(const int* __restrict__ ei, int* __restrict__ cursor, int* __restrict__ cols) {
  int e = blockIdx.x * 256 + threadIdx.x;
  if (e < EE) {
    int d = ei[EE + e], s = ei[e];
    int pos = atomicAdd(&cursor[d], 1);
    cols[pos] = s;
  }
}

__global__ void k_dinv0(const int* __restrict__ cnt, float* __restrict__ d2, float* __restrict__ d1) {
  int i = blockIdx.x * 256 + threadIdx.x;
  if (i < NN) {
    float c = (float)cnt[i];
    d2[i] = 1.f / sqrtf(c + 2.f);
    d1[i] = 1.f / sqrtf(c + 1.f);
  }
}

__global__ void k_pwnorm(const float* __restrict__ pw, float* __restrict__ pwn) {
  int l = blockIdx.x, t = threadIdx.x; // 64 threads
  float a = pw[l*H + t], b = pw[l*H + 64 + t];
  float s = a*a + b*b;
  for (int off = 32; off > 0; off >>= 1) s += __shfl_down(s, off);
  if (t == 0) pwn[l] = sqrtf(s);
}

__global__ void k_segS(const int* __restrict__ dst, const float* __restrict__ me, float* __restrict__ S) {
  int e = blockIdx.x * 256 + threadIdx.x;
  if (e < EE) {
    int d = dst[e];
#pragma unroll
    for (int m = 0; m < MEDGE; m++) atomicAdd(&S[d*MEDGE + m], me[e*MEDGE + m]);
  }
}

// ---------------- node_attr & matmuls ----------------
__global__ void k_na(const float* __restrict__ F, const float* __restrict__ mn,
                     const float* __restrict__ h, float* __restrict__ na) {
  int idx = blockIdx.x * 256 + threadIdx.x;
  if (idx >= NN * 140) return;
  int row = idx / 140, c = idx - row * 140;
  float v;
  if (c < NF) v = F[row*NF + c];
  else if (c < NF + MNODE) v = mn[row*MNODE + (c - NF)];
  else v = h[row*H + (c - NF - MNODE)];
  na[idx] = v;
}

// C[row,0:128] = A[row,:K] @ B[:K,0:128]  (B row-stride 128); optional row scale by dinv
__global__ void k_mm_rb(const float* __restrict__ A, int lda, const float* __restrict__ B,
                        float* __restrict__ C, int K, const float* __restrict__ dinv) {
  __shared__ float as[160];
  int row = blockIdx.x, t = threadIdx.x;
  float acc = 0.f;
  for (int k0 = 0; k0 < K; k0 += H) {
    int m = (K - k0 < H) ? (K - k0) : H;
    if (t < m) as[t] = A[(size_t)row*lda + k0 + t];
    __syncthreads();
    for (int kk = 0; kk < m; kk++) acc += as[kk] * B[(k0 + kk)*H + t];
    __syncthreads();
  }
  if (dinv) acc *= dinv[row];
  C[(size_t)row*H + t] = acc;
}

// SpMM over CSR rows; if dinv!=null apply GCN epilogue: dinv_i*(acc + fill*ts_i) + bias (+relu)
__global__ void k_spmm_fused(const float* __restrict__ ts, const int* __restrict__ rp,
                             const int* __restrict__ cols, const float* __restrict__ dinv,
                             float fill, const float* __restrict__ bias, int relu,
                             float* __restrict__ out) {
  int i = blockIdx.x, t = threadIdx.x;
  float acc = 0.f;
  int beg = rp[i], end = rp[i+1];
  for (int e = beg; e < end; e++) acc += ts[(size_t)cols[e]*H + t];
  float v;
  if (dinv) {
    v = dinv[i] * (acc + fill * ts[(size_t)i*H + t]) + bias[t];
    if (relu) v = fmaxf(v, 0.f);
  } else v = acc;
  out[(size_t)i*H + t] = v;
}

__global__ void k_h1(const float* __restrict__ P, const float* __restrict__ bm,
                     const float* __restrict__ AQ, const float* __restrict__ S,
                     const float* __restrict__ WmB, const int* __restrict__ cnt,
                     float* __restrict__ h1) {
  int i = blockIdx.x, t = threadIdx.x;
  float v = (float)cnt[i] * (P[(size_t)i*H + t] + bm[t]) + AQ[(size_t)i*H + t];
#pragma unroll
  for (int m = 0; m < MEDGE; m++) v += S[i*MEDGE + m] * WmB[m*H + t];
  h1[(size_t)i*H + t] = fmaxf(v, 0.f);
}

// ---------------- top-k pooling ----------------
// score + sortable key build + rank init, fused.
// key = (sortable(score) << 12) | (4095 - i)  -- matches jax.lax.top_k tie-break (lower idx wins)
__global__ void k_score(const float* __restrict__ x, const float* __restrict__ pw,
                        const float* __restrict__ pwn, float* __restrict__ score,
                        unsigned long long* __restrict__ keys, int* __restrict__ rank) {
  int row = blockIdx.x, t = threadIdx.x; // 64 threads
  float s = x[(size_t)row*H + t]*pw[t] + x[(size_t)row*H + 64 + t]*pw[64 + t];
  for (int off = 32; off > 0; off >>= 1) s += __shfl_down(s, off);
  if (t == 0) {
    float sc = tanhf(s / pwn[0]);
    score[row] = sc;
    float s2 = sc + 0.0f;                   // canonicalize -0.0 -> +0.0
    unsigned u = __float_as_uint(s2);
    u ^= (unsigned)(((int)u >> 31)) | 0x80000000u;  // ascending-sortable
    keys[row] = ((unsigned long long)u << 12) | (unsigned)(4095 - row);
    rank[row] = 0;
  }
}

// 2-D tiled rank count: block (bi,bj) compares i-stripe [bi*256..) vs j-tile [bj*256..).
// Padding keys are 0 and never compare greater than a real key (real keys have
// nonzero payload bits except the impossible NaN@i=4095 case).
__global__ void k_count_rank(const unsigned long long* __restrict__ keys, int n,
                             int* __restrict__ rank) {
  __shared__ unsigned long long sk[256];
  int t = threadIdx.x;
  int j = blockIdx.y * 256 + t;
  sk[t] = (j < n) ? keys[j] : 0ull;
  __syncthreads();
  int i = blockIdx.x * 256 + t;
  if (i >= n) return;
  unsigned long long ki = keys[i];
  int r = 0;
#pragma unroll 8
  for (int jj = 0; jj < 256; jj++) r += (sk[jj] > ki) ? 1 : 0;
  if (r) atomicAdd(&rank[i], r);
}

__global__ void k_select(const float* __restrict__ score, const int* __restrict__ rank,
                         int n, int k, int* __restrict__ perm, float* __restrict__ sv) {
  int i = blockIdx.x * 256 + threadIdx.x;
  if (i < n) {
    int r = rank[i];
    if (r < k) { perm[r] = i; sv[r] = score[i]; }
  }
}

__global__ void k_poolx(const float* __restrict__ x, const int* __restrict__ perm,
                        const float* __restrict__ sv, float* __restrict__ xp) {
  int r = blockIdx.x, t = threadIdx.x;
  xp[(size_t)r*H + t] = x[(size_t)perm[r]*H + t] * sv[r];
}

// A_820[r,c] = (A1@A1)[perm_r, perm_c], diag zeroed; A1 = offdiag(A0)+I via CSR
__global__ void k_a820(const int* __restrict__ rp, const int* __restrict__ cols,
                       const int* __restrict__ perm, float* __restrict__ A820) {
  __shared__ float acc[NN];
  int r = blockIdx.x, t = threadIdx.x;
  for (int i = t; i < NN; i += 256) acc[i] = 0.f;
  __syncthreads();
  int pi = perm[r];
  int beg = rp[pi], end = rp[pi+1];
  // k = pi term: + A1[pi,:]
  for (int e = beg + t; e < end; e += 256) { int c = cols[e]; if (c != pi) atomicAdd(&acc[c], 1.f); }
  if (t == 0) atomicAdd(&acc[pi], 1.f);
  // k != pi terms: for each off-diag edge instance (pi->c): + A1[c,:]
  for (int e0 = beg; e0 < end; e0++) {
    int c = cols[e0];
    if (c == pi) continue;
    int b2 = rp[c], e2 = rp[c+1];
    for (int e = b2 + t; e < e2; e += 256) { int c2 = cols[e]; if (c2 != c) atomicAdd(&acc[c2], 1.f); }
    if (t == 0) atomicAdd(&acc[c], 1.f);
  }
  __syncthreads();
  for (int cc = t; cc < 820; cc += 256)
    A820[(size_t)r*820 + cc] = (cc == r) ? 0.f : acc[perm[cc]];
}

// dense level augment+pool: out[r,c] = (A^2)[pr,pc] + 2*A[pr,pc]  (r!=c), 0 on diag; A has zero diag
__global__ void k_augpool(const float* __restrict__ A, int n, const int* __restrict__ perm,
                          int knext, float* __restrict__ out) {
  __shared__ float rowb[832];
  int r = blockIdx.x, t = threadIdx.x;
  int pr = perm[r];
  for (int i = t; i < n; i += 256) rowb[i] = A[(size_t)pr*n + i];
  __syncthreads();
  for (int c = t; c < knext; c += 256) {
    int pc = perm[c];
    float dot = 0.f;
    for (int kk = 0; kk < n; kk++) {
      float rv = rowb[kk];
      if (rv != 0.f) dot += rv * A[(size_t)kk*n + pc];
    }
    out[(size_t)r*knext + c] = (c == r) ? 0.f : (dot + 2.f * rowb[pc]);
  }
}

__global__ void k_rowsum_dinv(const float* __restrict__ A, int n, float fill, float* __restrict__ dv) {
  __shared__ float red[256];
  int r = blockIdx.x, t = threadIdx.x;
  float s = 0.f;
  for (int c = t; c < n; c += 256) s += A[(size_t)r*n + c];
  red[t] = s; __syncthreads();
  for (int off = 128; off > 0; off >>= 1) { if (t < off) red[t] += red[t+off]; __syncthreads(); }
  if (t == 0) dv[r] = 1.f / sqrtf(red[0] + fill);
}

// dense GCN apply: out[i,:] = dinv_i*(sum_k A[i,k]*ts[k,:] + fill*ts[i,:]) + b (+relu)
__global__ void k_dense_gcn(const float* __restrict__ A, int n, const float* __restrict__ ts,
                            const float* __restrict__ dinv, float fill, const float* __restrict__ bias,
                            int relu, float* __restrict__ out) {
  __shared__ float arow[128];
  int i = blockIdx.x, t = threadIdx.x;
  float acc = 0.f;
  for (int k0 = 0; k0 < n; k0 += H) {
    int m = (n - k0 < H) ? (n - k0) : H;
    if (t < m) arow[t] = A[(size_t)i*n + k0 + t];
    __syncthreads();
    for (int kk = 0; kk < m; kk++) {
      float a = arow[kk]; // uniform across block -> uniform branch
      if (a != 0.f) acc += a * ts[(size_t)(k0 + kk)*H + t];
    }
    __syncthreads();
  }
  float v = dinv[i] * (acc + fill * ts[(size_t)i*H + t]) + bias[t];
  if (relu) v = fmaxf(v, 0.f);
  out[(size_t)i*H + t] = v;
}

__global__ void k_scatter_add(float* __restrict__ tmp, const int* __restrict__ perm,
                              const float* __restrict__ xc) {
  int r = blockIdx.x, t = threadIdx.x;
  tmp[(size_t)perm[r]*H + t] += xc[(size_t)r*H + t];
}

__global__ void k_relu(const float* __restrict__ x, float* __restrict__ y, int count) {
  int i = blockIdx.x * 256 + threadIdx.x;
  if (i < count) y[i] = fmaxf(x[i], 0.f);
}

// ts2[row,0:4] = dinv1_row * (cat([h1,h2r]) @ Wout)[row,:]
__global__ void k_outproj(const float* __restrict__ h1, const float* __restrict__ h2r,
                          const float* __restrict__ Wout, const float* __restrict__ dinv1,
                          float* __restrict__ ts2) {
  int row = blockIdx.x, t = threadIdx.x; // 64 threads
  float p0 = 0.f, p1 = 0.f, p2 = 0.f, p3 = 0.f;
#pragma unroll
  for (int half = 0; half < 2; half++) {
    float a = h1[(size_t)row*H + half*64 + t];
    const float* w = Wout + (half*64 + t)*4;
    p0 += a*w[0]; p1 += a*w[1]; p2 += a*w[2]; p3 += a*w[3];
    float b = h2r[(size_t)row*H + half*64 + t];
    const float* w2 = Wout + (128 + half*64 + t)*4;
    p0 += b*w2[0]; p1 += b*w2[1]; p2 += b*w2[2]; p3 += b*w2[3];
  }
  for (int off = 32; off > 0; off >>= 1) {
    p0 += __shfl_down(p0, off); p1 += __shfl_down(p1, off);
    p2 += __shfl_down(p2, off); p3 += __shfl_down(p3, off);
  }
  if (t == 0) {
    float d = dinv1[row];
    ts2[row*4+0] = d*p0; ts2[row*4+1] = d*p1; ts2[row*4+2] = d*p2; ts2[row*4+3] = d*p3;
  }
}

__global__ void k_gcn_out(const float* __restrict__ ts2, const int* __restrict__ rp,
                          const int* __restrict__ cols, const float* __restrict__ dinv1,
                          const float* __restrict__ bout, float* __restrict__ Fcur,
                          float* __restrict__ dout, int tstep) {
  int i = blockIdx.x, t = threadIdx.x; // 64 threads
  int f = t & 3;
  float acc = 0.f;
  int beg = rp[i], end = rp[i+1];
  for (int e = beg + (t >> 2); e < end; e += 16) acc += ts2[cols[e]*4 + f];
  for (int off = 32; off >= 4; off >>= 1) acc += __shfl_down(acc, off);
  if (t < 4) {
    float v = dinv1[i] * (acc + ts2[i*4 + f]) + bout[f];
    Fcur[i*4 + f] = v;
    dout[i*(NT*NF) + tstep*NF + f] = v;
  }
}

extern "C" void kernel_launch(void* const* d_in, const int* in_sizes, int n_in,
                              void* d_out, int out_size, void* d_ws, size_t ws_size,
                              hipStream_t stream) {
  const float* F0        = (const float*)d_in[0];
  const float* mesh_node = (const float*)d_in[1];
  const float* mesh_edge = (const float*)d_in[2];
  const float* Wm        = (const float*)d_in[3];
  const float* bm        = (const float*)d_in[4];
  const float* Wd0       = (const float*)d_in[5];
  const float* bd0       = (const float*)d_in[6];
  const float* Wd        = (const float*)d_in[7];
  const float* bd        = (const float*)d_in[8];
  const float* pool_w    = (const float*)d_in[9];
  const float* Wu        = (const float*)d_in[10];
  const float* bu        = (const float*)d_in[11];
  const float* Wout      = (const float*)d_in[12];
  const float* bout      = (const float*)d_in[13];
  const int*   ei        = (const int*)d_in[14];
  float* out = (float*)d_out;

  char* p = (char*)d_ws;
  auto carve = [&](size_t bytes) -> char* {
    char* r = p;
    p += (bytes + 255) & ~(size_t)255;
    return r;
  };
  int*   cnt    = (int*)carve((size_t)NN*4);
  int*   rp     = (int*)carve((size_t)(NN+1)*4);
  int*   cursor = (int*)carve((size_t)NN*4);
  int*   cols   = (int*)carve((size_t)EE*4);
  int*   permb  = (int*)carve((size_t)5*832*4);
  float* svb    = (float*)carve((size_t)5*832*4);
  float* dinv2  = (float*)carve((size_t)NN*4);
  float* dinv1  = (float*)carve((size_t)NN*4);
  float* pwn    = (float*)carve(8*4);
  float* S      = (float*)carve((size_t)NN*MEDGE*4);
  float* na     = (float*)carve((size_t)NN*140*4);
  float* P      = (float*)carve((size_t)NN*H*4);
  float* Q      = (float*)carve((size_t)NN*H*4);
  float* h1     = (float*)carve((size_t)NN*H*4);
  float* hbuf   = (float*)carve((size_t)NN*H*4);
  float* h2r    = (float*)carve((size_t)NN*H*4);
  float* tsb    = (float*)carve((size_t)NN*H*4);
  float* tmp    = (float*)carve((size_t)NN*H*4);   // also AQ scratch
  float* x0     = (float*)carve((size_t)NN*H*4);
  float* x1     = (float*)carve((size_t)820*H*4);
  float* x2     = (float*)carve((size_t)164*H*4);
  float* x3     = (float*)carve((size_t)33*H*4);
  float* x4     = (float*)carve((size_t)7*H*4);
  float* xp     = (float*)carve((size_t)820*H*4);
  float* xcur   = (float*)carve((size_t)820*H*4);
  float* score  = (float*)carve((size_t)NN*4);
  unsigned long long* keysb = (unsigned long long*)carve((size_t)NN*8);
  int*   rankb  = (int*)carve((size_t)NN*4);
  float* A820   = (float*)carve((size_t)820*820*4);
  float* A164   = (float*)carve((size_t)164*164*4);
  float* A33    = (float*)carve((size_t)33*33*4);
  float* A7     = (float*)carve((size_t)7*7*4);
  float* A2b    = (float*)carve((size_t)2*2*4);
  float* dv820  = (float*)carve(820*4);
  float* dv164  = (float*)carve(164*4);
  float* dv33   = (float*)carve(33*4);
  float* dv7    = (float*)carve(7*4);
  float* dv2    = (float*)carve(2*4);
  float* ts2    = (float*)carve((size_t)NN*NF*4);
  float* Fcur   = (float*)carve((size_t)NN*NF*4);

  const int KLh[5]  = {820, 164, 33, 7, 2};
  const int szs[5]  = {4096, 820, 164, 33, 7};
  float* Adense[5] = {A820, A164, A33, A7, A2b};
  float* dvl[5]    = {dv820, dv164, dv33, dv7, dv2};
  float* xsv[5]    = {x0, x1, x2, x3, x4};
  int* perml[5]; float* svl[5];
  for (int l = 0; l < 5; l++) { perml[l] = permb + l*832; svl[l] = svb + l*832; }

  // ---- setup (once per launch) ----
  hipMemsetAsync(cnt, 0, (size_t)NN*4, stream);
  hipMemsetAsync(S, 0, (size_t)NN*MEDGE*4, stream);
  hipMemsetAsync(hbuf, 0, (size_t)NN*H*4, stream);
  k_count<<<EE/256, 256, 0, stream>>>(ei + EE, cnt);
  k_scan<<<1, 1024, 0, stream>>>(cnt, rp);
  hipMemcpyAsync(cursor, rp, (size_t)NN*4, hipMemcpyDeviceToDevice, stream);
  k_fill<<<EE/256, 256, 0, stream>>>(ei, cursor, cols);
  k_dinv0<<<NN/256, 256, 0, stream>>>(cnt, dinv2, dinv1);
  k_pwnorm<<<5, 64, 0, stream>>>(pool_w, pwn);
  k_segS<<<EE/256, 256, 0, stream>>>(ei + EE, mesh_edge, S);
  hipMemcpyAsync(Fcur, F0, (size_t)NN*NF*4, hipMemcpyDeviceToDevice, stream);

  for (int step = 0; step < NT; step++) {
    // edge MLP (factored) -> h1
    k_na<<<(NN*140 + 255)/256, 256, 0, stream>>>(Fcur, mesh_node, hbuf, na);
    k_mm_rb<<<NN, 128, 0, stream>>>(na, 140, Wm, P, 140, nullptr);
    k_mm_rb<<<NN, 128, 0, stream>>>(na, 140, Wm + 140*H, Q, 140, nullptr);
    k_spmm_fused<<<NN, 128, 0, stream>>>(Q, rp, cols, nullptr, 0.f, nullptr, 0, tmp); // AQ
    k_h1<<<NN, 128, 0, stream>>>(P, bm, tmp, S, Wm + 280*H, cnt, h1);

    // down GCN0 at 4096 (fill=2), relu
    k_mm_rb<<<NN, 128, 0, stream>>>(h1, H, Wd0, tsb, H, dinv2);
    k_spmm_fused<<<NN, 128, 0, stream>>>(tsb, rp, cols, dinv2, 2.f, bd0, 1, x0);

    // down path
    for (int i = 0; i < 5; i++) {
      int n_prev = szs[i], k = KLh[i];
      int gb = (n_prev + 255) / 256;
      k_score<<<n_prev, 64, 0, stream>>>(xsv[i], pool_w + i*H, pwn + i, score, keysb, rankb);
      k_count_rank<<<dim3(gb, gb), 256, 0, stream>>>(keysb, n_prev, rankb);
      k_select<<<gb, 256, 0, stream>>>(score, rankb, n_prev, k, perml[i], svl[i]);
      k_poolx<<<k, 128, 0, stream>>>(xsv[i], perml[i], svl[i], xp);
      if (i == 0) k_a820<<<820, 256, 0, stream>>>(rp, cols, perml[0], Adense[0]);
      else        k_augpool<<<k, 256, 0, stream>>>(Adense[i-1], n_prev, perml[i], k, Adense[i]);
      k_rowsum_dinv<<<k, 256, 0, stream>>>(Adense[i], k, 2.f, dvl[i]);
      k_mm_rb<<<k, 128, 0, stream>>>(xp, H, Wd + i*H*H, tsb, H, dvl[i]);
      float* outx = (i < 4) ? xsv[i+1] : xcur;
      k_dense_gcn<<<k, 128, 0, stream>>>(Adense[i], k, tsb, dvl[i], 2.f, bd + i*H, 1, outx);
    }

    // up path
    for (int i = 0; i < 5; i++) {
      int j = 4 - i;
      int n = szs[j], kk = KLh[j];
      hipMemcpyAsync(tmp, xsv[j], (size_t)n*H*4, hipMemcpyDeviceToDevice, stream);
      k_scatter_add<<<kk, 128, 0, stream>>>(tmp, perml[j], xcur);
      if (j > 0) {
        k_mm_rb<<<n, 128, 0, stream>>>(tmp, H, Wu + i*H*H, tsb, H, dvl[j-1]);
        k_dense_gcn<<<n, 128, 0, stream>>>(Adense[j-1], n, tsb, dvl[j-1], 2.f, bu + i*H,
                                           (i < 4) ? 1 : 0, xcur);
      } else {
        k_mm_rb<<<n, 128, 0, stream>>>(tmp, H, Wu + i*H*H, tsb, H, dinv2);
        k_spmm_fused<<<n, 128, 0, stream>>>(tsb, rp, cols, dinv2, 2.f, bu + i*H, 0, hbuf);
      }
    }

    // output GCN (fill=1)
    k_relu<<<(NN*H + 255)/256, 256, 0, stream>>>(hbuf, h2r, NN*H);
    k_outproj<<<NN, 64, 0, stream>>>(h1, h2r, Wout, dinv1, ts2);
    k_gcn_out<<<NN, 64, 0, stream>>>(ts2, rp, cols, dinv1, bout, Fcur, out, step);
  }
}

// Round 3
// 1165.041 us; speedup vs baseline: 1.2026x; 1.0902x over previous
//
#include <hip/hip_runtime.h>
#include <math.h>

#define NN 4096
#define EE 65536
#define H 128
#define NF 4
#define MNODE 8
#define MEDGE 4
#define NT 2

// ---------------- CSR build ----------------
__global__ void k_count(const int* __restrict__ dst, int* __restrict__ cnt) {
  int e = blockIdx.x * 256 + threadIdx.x;
  if (e < EE) atomicAdd(&cnt[dst[e]], 1);
}

__global__ void k_scan(const int* __restrict__ cnt, int* __restrict__ rp) {
  __shared__ int sh[1024];
  int t = threadIdx.x;
  int v0 = cnt[4*t], v1 = cnt[4*t+1], v2 = cnt[4*t+2], v3 = cnt[4*t+3];
  int p1 = v0, p2 = v0 + v1, p3 = p2 + v2, tot = p3 + v3;
  sh[t] = tot; __syncthreads();
  for (int off = 1; off < 1024; off <<= 1) {
    int add = (t >= off) ? sh[t-off] : 0;
    __syncthreads();
    sh[t] += add;
    __syncthreads();
  }
  int base = sh[t] - tot;
  rp[4*t] = base; rp[4*t+1] = base + p1; rp[4*t+2] = base + p2; rp[4*t+3] = base + p3;
  if (t == 1023) rp[NN] = sh[t];
}

__global__ void k_fill(const int* __restrict__ ei, int* __restrict__ cursor, int* __restrict__ cols) {
  int e = blockIdx.x * 256 + threadIdx.x;
  if (e < EE) {
    int d = ei[EE + e], s = ei[e];
    int pos = atomicAdd(&cursor[d], 1);
    cols[pos] = s;
  }
}

__global__ void k_dinv0(const int* __restrict__ cnt, float* __restrict__ d2, float* __restrict__ d1) {
  int i = blockIdx.x * 256 + threadIdx.x;
  if (i < NN) {
    float c = (float)cnt[i];
    d2[i] = 1.f / sqrtf(c + 2.f);
    d1[i] = 1.f / sqrtf(c + 1.f);
  }
}

__global__ void k_pwnorm(const float* __restrict__ pw, float* __restrict__ pwn) {
  int l = blockIdx.x, t = threadIdx.x; // 64 threads
  float a = pw[l*H + t], b = pw[l*H + 64 + t];
  float s = a*a + b*b;
  for (int off = 32; off > 0; off >>= 1) s += __shfl_down(s, off);
  if (t == 0) pwn[l] = sqrtf(s);
}

__global__ void k_segS(const int* __restrict__ dst, const float* __restrict__ me, float* __restrict__ S) {
  int e = blockIdx.x * 256 + threadIdx.x;
  if (e < EE) {
    int d = dst[e];
#pragma unroll
    for (int m = 0; m < MEDGE; m++) atomicAdd(&S[d*MEDGE + m], me[e*MEDGE + m]);
  }
}

// ---------------- node_attr & matmuls ----------------
__global__ void k_na(const float* __restrict__ F, const float* __restrict__ mn,
                     const float* __restrict__ h, float* __restrict__ na) {
  int idx = blockIdx.x * 256 + threadIdx.x;
  if (idx >= NN * 140) return;
  int row = idx / 140, c = idx - row * 140;
  float v;
  if (c < NF) v = F[row*NF + c];
  else if (c < NF + MNODE) v = mn[row*MNODE + (c - NF)];
  else v = h[row*H + (c - NF - MNODE)];
  na[idx] = v;
}

// C[row,0:128] = A[row,:K] @ B[:K,0:128]  (B row-stride 128); optional row scale by dinv
__global__ void k_mm_rb(const float* __restrict__ A, int lda, const float* __restrict__ B,
                        float* __restrict__ C, int K, const float* __restrict__ dinv) {
  __shared__ float as[160];
  int row = blockIdx.x, t = threadIdx.x;
  float acc = 0.f;
  for (int k0 = 0; k0 < K; k0 += H) {
    int m = (K - k0 < H) ? (K - k0) : H;
    if (t < m) as[t] = A[(size_t)row*lda + k0 + t];
    __syncthreads();
    for (int kk = 0; kk < m; kk++) acc += as[kk] * B[(k0 + kk)*H + t];
    __syncthreads();
  }
  if (dinv) acc *= dinv[row];
  C[(size_t)row*H + t] = acc;
}

// SpMM over CSR rows; if dinv!=null apply GCN epilogue: dinv_i*(acc + fill*ts_i) + bias (+relu)
__global__ void k_spmm_fused(const float* __restrict__ ts, const int* __restrict__ rp,
                             const int* __restrict__ cols, const float* __restrict__ dinv,
                             float fill, const float* __restrict__ bias, int relu,
                             float* __restrict__ out) {
  int i = blockIdx.x, t = threadIdx.x;
  float acc = 0.f;
  int beg = rp[i], end = rp[i+1];
  for (int e = beg; e < end; e++) acc += ts[(size_t)cols[e]*H + t];
  float v;
  if (dinv) {
    v = dinv[i] * (acc + fill * ts[(size_t)i*H + t]) + bias[t];
    if (relu) v = fmaxf(v, 0.f);
  } else v = acc;
  out[(size_t)i*H + t] = v;
}

__global__ void k_h1(const float* __restrict__ P, const float* __restrict__ bm,
                     const float* __restrict__ AQ, const float* __restrict__ S,
                     const float* __restrict__ WmB, const int* __restrict__ cnt,
                     float* __restrict__ h1) {
  int i = blockIdx.x, t = threadIdx.x;
  float v = (float)cnt[i] * (P[(size_t)i*H + t] + bm[t]) + AQ[(size_t)i*H + t];
#pragma unroll
  for (int m = 0; m < MEDGE; m++) v += S[i*MEDGE + m] * WmB[m*H + t];
  h1[(size_t)i*H + t] = fmaxf(v, 0.f);
}

// ---------------- top-k pooling ----------------
// score + sortable key build + rank init, fused.
// key = (sortable(score) << 12) | (4095 - i)  -- matches jax.lax.top_k tie-break (lower idx wins)
__global__ void k_score(const float* __restrict__ x, const float* __restrict__ pw,
                        const float* __restrict__ pwn, float* __restrict__ score,
                        unsigned long long* __restrict__ keys, int* __restrict__ rank) {
  int row = blockIdx.x, t = threadIdx.x; // 64 threads
  float s = x[(size_t)row*H + t]*pw[t] + x[(size_t)row*H + 64 + t]*pw[64 + t];
  for (int off = 32; off > 0; off >>= 1) s += __shfl_down(s, off);
  if (t == 0) {
    float sc = tanhf(s / pwn[0]);
    score[row] = sc;
    float s2 = sc + 0.0f;                   // canonicalize -0.0 -> +0.0
    unsigned u = __float_as_uint(s2);
    u ^= (unsigned)(((int)u >> 31)) | 0x80000000u;  // ascending-sortable
    keys[row] = ((unsigned long long)u << 12) | (unsigned)(4095 - row);
    rank[row] = 0;
  }
}

// 2-D tiled rank count: block (bi,bj) compares i-stripe [bi*256..) vs j-tile [bj*256..).
__global__ void k_count_rank(const unsigned long long* __restrict__ keys, int n,
                             int* __restrict__ rank) {
  __shared__ unsigned long long sk[256];
  int t = threadIdx.x;
  int j = blockIdx.y * 256 + t;
  sk[t] = (j < n) ? keys[j] : 0ull;
  __syncthreads();
  int i = blockIdx.x * 256 + t;
  if (i >= n) return;
  unsigned long long ki = keys[i];
  int r = 0;
#pragma unroll 8
  for (int jj = 0; jj < 256; jj++) r += (sk[jj] > ki) ? 1 : 0;
  if (r) atomicAdd(&rank[i], r);
}

__global__ void k_select(const float* __restrict__ score, const int* __restrict__ rank,
                         int n, int k, int* __restrict__ perm, float* __restrict__ sv) {
  int i = blockIdx.x * 256 + threadIdx.x;
  if (i < n) {
    int r = rank[i];
    if (r < k) { perm[r] = i; sv[r] = score[i]; }
  }
}

__global__ void k_poolx(const float* __restrict__ x, const int* __restrict__ perm,
                        const float* __restrict__ sv, float* __restrict__ xp) {
  int r = blockIdx.x, t = threadIdx.x;
  xp[(size_t)r*H + t] = x[(size_t)perm[r]*H + t] * sv[r];
}

// A_820[r,c] = (A1@A1)[perm_r, perm_c], diag zeroed; A1 = offdiag(A0)+I via CSR
__global__ void k_a820(const int* __restrict__ rp, const int* __restrict__ cols,
                       const int* __restrict__ perm, float* __restrict__ A820) {
  __shared__ float acc[NN];
  int r = blockIdx.x, t = threadIdx.x;
  for (int i = t; i < NN; i += 256) acc[i] = 0.f;
  __syncthreads();
  int pi = perm[r];
  int beg = rp[pi], end = rp[pi+1];
  // k = pi term: + A1[pi,:]
  for (int e = beg + t; e < end; e += 256) { int c = cols[e]; if (c != pi) atomicAdd(&acc[c], 1.f); }
  if (t == 0) atomicAdd(&acc[pi], 1.f);
  // k != pi terms: for each off-diag edge instance (pi->c): + A1[c,:]
  for (int e0 = beg; e0 < end; e0++) {
    int c = cols[e0];
    if (c == pi) continue;
    int b2 = rp[c], e2 = rp[c+1];
    for (int e = b2 + t; e < e2; e += 256) { int c2 = cols[e]; if (c2 != c) atomicAdd(&acc[c2], 1.f); }
    if (t == 0) atomicAdd(&acc[c], 1.f);
  }
  __syncthreads();
  for (int cc = t; cc < 820; cc += 256)
    A820[(size_t)r*820 + cc] = (cc == r) ? 0.f : acc[perm[cc]];
}

// column pre-gather: AP[kk][c] = A[kk][perm[c]]   (n x knext, row-major)
__global__ void k_gathercols(const float* __restrict__ A, int n, const int* __restrict__ perm,
                             int knext, float* __restrict__ AP) {
  int idx = blockIdx.x * 256 + threadIdx.x;
  int total = n * knext;
  if (idx >= total) return;
  int kk = idx / knext, c = idx - kk * knext;
  AP[idx] = A[(size_t)kk * n + perm[c]];
}

// dense level augment+pool via pre-gathered columns:
// out[r][c] = sum_kk A[pr][kk] * AP[kk][c] + 2*AP[pr][c]   (r!=c), 0 on diag
// (dense accumulate: zero entries contribute exactly 0; values are integer counts)
__global__ void k_augpool2(const float* __restrict__ A, const float* __restrict__ AP,
                           int n, const int* __restrict__ perm, int knext,
                           float* __restrict__ out) {
  __shared__ float rowb[832];
  int r = blockIdx.x, t = threadIdx.x;
  int pr = perm[r];
  for (int i = t; i < n; i += 256) rowb[i] = A[(size_t)pr*n + i];
  __syncthreads();
  for (int c = t; c < knext; c += 256) {
    float dot = 0.f;
#pragma unroll 8
    for (int kk = 0; kk < n; kk++) dot += rowb[kk] * AP[(size_t)kk*knext + c];
    out[(size_t)r*knext + c] = (c == r) ? 0.f : (dot + 2.f * AP[(size_t)pr*knext + c]);
  }
}

__global__ void k_rowsum_dinv(const float* __restrict__ A, int n, float fill, float* __restrict__ dv) {
  __shared__ float red[256];
  int r = blockIdx.x, t = threadIdx.x;
  float s = 0.f;
  for (int c = t; c < n; c += 256) s += A[(size_t)r*n + c];
  red[t] = s; __syncthreads();
  for (int off = 128; off > 0; off >>= 1) { if (t < off) red[t] += red[t+off]; __syncthreads(); }
  if (t == 0) dv[r] = 1.f / sqrtf(red[0] + fill);
}

// dense GCN apply: out[i,:] = dinv_i*(sum_k A[i,k]*ts[k,:] + fill*ts[i,:]) + b (+relu)
__global__ void k_dense_gcn(const float* __restrict__ A, int n, const float* __restrict__ ts,
                            const float* __restrict__ dinv, float fill, const float* __restrict__ bias,
                            int relu, float* __restrict__ out) {
  __shared__ float arow[128];
  int i = blockIdx.x, t = threadIdx.x;
  float acc = 0.f;
  for (int k0 = 0; k0 < n; k0 += H) {
    int m = (n - k0 < H) ? (n - k0) : H;
    if (t < m) arow[t] = A[(size_t)i*n + k0 + t];
    __syncthreads();
    for (int kk = 0; kk < m; kk++) {
      float a = arow[kk]; // uniform across block -> uniform branch
      if (a != 0.f) acc += a * ts[(size_t)(k0 + kk)*H + t];
    }
    __syncthreads();
  }
  float v = dinv[i] * (acc + fill * ts[(size_t)i*H + t]) + bias[t];
  if (relu) v = fmaxf(v, 0.f);
  out[(size_t)i*H + t] = v;
}

__global__ void k_scatter_add(float* __restrict__ tmp, const int* __restrict__ perm,
                              const float* __restrict__ xc) {
  int r = blockIdx.x, t = threadIdx.x;
  tmp[(size_t)perm[r]*H + t] += xc[(size_t)r*H + t];
}

__global__ void k_relu(const float* __restrict__ x, float* __restrict__ y, int count) {
  int i = blockIdx.x * 256 + threadIdx.x;
  if (i < count) y[i] = fmaxf(x[i], 0.f);
}

// ts2[row,0:4] = dinv1_row * (cat([h1,h2r]) @ Wout)[row,:]
__global__ void k_outproj(const float* __restrict__ h1, const float* __restrict__ h2r,
                          const float* __restrict__ Wout, const float* __restrict__ dinv1,
                          float* __restrict__ ts2) {
  int row = blockIdx.x, t = threadIdx.x; // 64 threads
  float p0 = 0.f, p1 = 0.f, p2 = 0.f, p3 = 0.f;
#pragma unroll
  for (int half = 0; half < 2; half++) {
    float a = h1[(size_t)row*H + half*64 + t];
    const float* w = Wout + (half*64 + t)*4;
    p0 += a*w[0]; p1 += a*w[1]; p2 += a*w[2]; p3 += a*w[3];
    float b = h2r[(size_t)row*H + half*64 + t];
    const float* w2 = Wout + (128 + half*64 + t)*4;
    p0 += b*w2[0]; p1 += b*w2[1]; p2 += b*w2[2]; p3 += b*w2[3];
  }
  for (int off = 32; off > 0; off >>= 1) {
    p0 += __shfl_down(p0, off); p1 += __shfl_down(p1, off);
    p2 += __shfl_down(p2, off); p3 += __shfl_down(p3, off);
  }
  if (t == 0) {
    float d = dinv1[row];
    ts2[row*4+0] = d*p0; ts2[row*4+1] = d*p1; ts2[row*4+2] = d*p2; ts2[row*4+3] = d*p3;
  }
}

__global__ void k_gcn_out(const float* __restrict__ ts2, const int* __restrict__ rp,
                          const int* __restrict__ cols, const float* __restrict__ dinv1,
                          const float* __restrict__ bout, float* __restrict__ Fcur,
                          float* __restrict__ dout, int tstep) {
  int i = blockIdx.x, t = threadIdx.x; // 64 threads
  int f = t & 3;
  float acc = 0.f;
  int beg = rp[i], end = rp[i+1];
  for (int e = beg + (t >> 2); e < end; e += 16) acc += ts2[cols[e]*4 + f];
  for (int off = 32; off >= 4; off >>= 1) acc += __shfl_down(acc, off);
  if (t < 4) {
    float v = dinv1[i] * (acc + ts2[i*4 + f]) + bout[f];
    Fcur[i*4 + f] = v;
    dout[i*(NT*NF) + tstep*NF + f] = v;
  }
}

extern "C" void kernel_launch(void* const* d_in, const int* in_sizes, int n_in,
                              void* d_out, int out_size, void* d_ws, size_t ws_size,
                              hipStream_t stream) {
  const float* F0        = (const float*)d_in[0];
  const float* mesh_node = (const float*)d_in[1];
  const float* mesh_edge = (const float*)d_in[2];
  const float* Wm        = (const float*)d_in[3];
  const float* bm        = (const float*)d_in[4];
  const float* Wd0       = (const float*)d_in[5];
  const float* bd0       = (const float*)d_in[6];
  const float* Wd        = (const float*)d_in[7];
  const float* bd        = (const float*)d_in[8];
  const float* pool_w    = (const float*)d_in[9];
  const float* Wu        = (const float*)d_in[10];
  const float* bu        = (const float*)d_in[11];
  const float* Wout      = (const float*)d_in[12];
  const float* bout      = (const float*)d_in[13];
  const int*   ei        = (const int*)d_in[14];
  float* out = (float*)d_out;

  char* p = (char*)d_ws;
  auto carve = [&](size_t bytes) -> char* {
    char* r = p;
    p += (bytes + 255) & ~(size_t)255;
    return r;
  };
  int*   cnt    = (int*)carve((size_t)NN*4);
  int*   rp     = (int*)carve((size_t)(NN+1)*4);
  int*   cursor = (int*)carve((size_t)NN*4);
  int*   cols   = (int*)carve((size_t)EE*4);
  int*   permb  = (int*)carve((size_t)5*832*4);
  float* svb    = (float*)carve((size_t)5*832*4);
  float* dinv2  = (float*)carve((size_t)NN*4);
  float* dinv1  = (float*)carve((size_t)NN*4);
  float* pwn    = (float*)carve(8*4);
  float* S      = (float*)carve((size_t)NN*MEDGE*4);
  float* na     = (float*)carve((size_t)NN*140*4);
  float* P      = (float*)carve((size_t)NN*H*4);
  float* Q      = (float*)carve((size_t)NN*H*4);
  float* h1     = (float*)carve((size_t)NN*H*4);
  float* hbuf   = (float*)carve((size_t)NN*H*4);
  float* h2r    = (float*)carve((size_t)NN*H*4);
  float* tsb    = (float*)carve((size_t)NN*H*4);
  float* tmp    = (float*)carve((size_t)NN*H*4);   // AQ scratch; also AP scratch in down path
  float* x0     = (float*)carve((size_t)NN*H*4);
  float* x1     = (float*)carve((size_t)820*H*4);
  float* x2     = (float*)carve((size_t)164*H*4);
  float* x3     = (float*)carve((size_t)33*H*4);
  float* x4     = (float*)carve((size_t)7*H*4);
  float* xp     = (float*)carve((size_t)820*H*4);
  float* xcur   = (float*)carve((size_t)820*H*4);
  float* score  = (float*)carve((size_t)NN*4);
  unsigned long long* keysb = (unsigned long long*)carve((size_t)NN*8);
  int*   rankb  = (int*)carve((size_t)NN*4);
  float* A820   = (float*)carve((size_t)820*820*4);
  float* A164   = (float*)carve((size_t)164*164*4);
  float* A33    = (float*)carve((size_t)33*33*4);
  float* A7     = (float*)carve((size_t)7*7*4);
  float* A2b    = (float*)carve((size_t)2*2*4);
  float* dv820  = (float*)carve(820*4);
  float* dv164  = (float*)carve(164*4);
  float* dv33   = (float*)carve(33*4);
  float* dv7    = (float*)carve(7*4);
  float* dv2    = (float*)carve(2*4);
  float* ts2    = (float*)carve((size_t)NN*NF*4);
  float* Fcur   = (float*)carve((size_t)NN*NF*4);

  // AP aliases tmp: tmp is dead between k_h1 (consumes AQ) and the up-path memcpy.
  // Max AP size = 820*164*4 = 537,920 B << NN*H*4 = 2 MB.
  float* AP = tmp;

  const int KLh[5]  = {820, 164, 33, 7, 2};
  const int szs[5]  = {4096, 820, 164, 33, 7};
  float* Adense[5] = {A820, A164, A33, A7, A2b};
  float* dvl[5]    = {dv820, dv164, dv33, dv7, dv2};
  float* xsv[5]    = {x0, x1, x2, x3, x4};
  int* perml[5]; float* svl[5];
  for (int l = 0; l < 5; l++) { perml[l] = permb + l*832; svl[l] = svb + l*832; }

  // ---- setup (once per launch) ----
  hipMemsetAsync(cnt, 0, (size_t)NN*4, stream);
  hipMemsetAsync(S, 0, (size_t)NN*MEDGE*4, stream);
  hipMemsetAsync(hbuf, 0, (size_t)NN*H*4, stream);
  k_count<<<EE/256, 256, 0, stream>>>(ei + EE, cnt);
  k_scan<<<1, 1024, 0, stream>>>(cnt, rp);
  hipMemcpyAsync(cursor, rp, (size_t)NN*4, hipMemcpyDeviceToDevice, stream);
  k_fill<<<EE/256, 256, 0, stream>>>(ei, cursor, cols);
  k_dinv0<<<NN/256, 256, 0, stream>>>(cnt, dinv2, dinv1);
  k_pwnorm<<<5, 64, 0, stream>>>(pool_w, pwn);
  k_segS<<<EE/256, 256, 0, stream>>>(ei + EE, mesh_edge, S);
  hipMemcpyAsync(Fcur, F0, (size_t)NN*NF*4, hipMemcpyDeviceToDevice, stream);

  for (int step = 0; step < NT; step++) {
    // edge MLP (factored) -> h1
    k_na<<<(NN*140 + 255)/256, 256, 0, stream>>>(Fcur, mesh_node, hbuf, na);
    k_mm_rb<<<NN, 128, 0, stream>>>(na, 140, Wm, P, 140, nullptr);
    k_mm_rb<<<NN, 128, 0, stream>>>(na, 140, Wm + 140*H, Q, 140, nullptr);
    k_spmm_fused<<<NN, 128, 0, stream>>>(Q, rp, cols, nullptr, 0.f, nullptr, 0, tmp); // AQ
    k_h1<<<NN, 128, 0, stream>>>(P, bm, tmp, S, Wm + 280*H, cnt, h1);

    // down GCN0 at 4096 (fill=2), relu
    k_mm_rb<<<NN, 128, 0, stream>>>(h1, H, Wd0, tsb, H, dinv2);
    k_spmm_fused<<<NN, 128, 0, stream>>>(tsb, rp, cols, dinv2, 2.f, bd0, 1, x0);

    // down path
    for (int i = 0; i < 5; i++) {
      int n_prev = szs[i], k = KLh[i];
      int gb = (n_prev + 255) / 256;
      k_score<<<n_prev, 64, 0, stream>>>(xsv[i], pool_w + i*H, pwn + i, score, keysb, rankb);
      k_count_rank<<<dim3(gb, gb), 256, 0, stream>>>(keysb, n_prev, rankb);
      k_select<<<gb, 256, 0, stream>>>(score, rankb, n_prev, k, perml[i], svl[i]);
      k_poolx<<<k, 128, 0, stream>>>(xsv[i], perml[i], svl[i], xp);
      if (i == 0) {
        k_a820<<<820, 256, 0, stream>>>(rp, cols, perml[0], Adense[0]);
      } else {
        int tot = n_prev * k;
        k_gathercols<<<(tot + 255)/256, 256, 0, stream>>>(Adense[i-1], n_prev, perml[i], k, AP);
        k_augpool2<<<k, 256, 0, stream>>>(Adense[i-1], AP, n_prev, perml[i], k, Adense[i]);
      }
      k_rowsum_dinv<<<k, 256, 0, stream>>>(Adense[i], k, 2.f, dvl[i]);
      k_mm_rb<<<k, 128, 0, stream>>>(xp, H, Wd + i*H*H, tsb, H, dvl[i]);
      float* outx = (i < 4) ? xsv[i+1] : xcur;
      k_dense_gcn<<<k, 128, 0, stream>>>(Adense[i], k, tsb, dvl[i], 2.f, bd + i*H, 1, outx);
    }

    // up path
    for (int i = 0; i < 5; i++) {
      int j = 4 - i;
      int n = szs[j], kk = KLh[j];
      hipMemcpyAsync(tmp, xsv[j], (size_t)n*H*4, hipMemcpyDeviceToDevice, stream);
      k_scatter_add<<<kk, 128, 0, stream>>>(tmp, perml[j], xcur);
      if (j > 0) {
        k_mm_rb<<<n, 128, 0, stream>>>(tmp, H, Wu + i*H*H, tsb, H, dvl[j-1]);
        k_dense_gcn<<<n, 128, 0, stream>>>(Adense[j-1], n, tsb, dvl[j-1], 2.f, bu + i*H,
                                           (i < 4) ? 1 : 0, xcur);
      } else {
        k_mm_rb<<<n, 128, 0, stream>>>(tmp, H, Wu + i*H*H, tsb, H, dinv2);
        k_spmm_fused<<<n, 128, 0, stream>>>(tsb, rp, cols, dinv2, 2.f, bu + i*H, 0, hbuf);
      }
    }

    // output GCN (fill=1)
    k_relu<<<(NN*H + 255)/256, 256, 0, stream>>>(hbuf, h2r, NN*H);
    k_outproj<<<NN, 64, 0, stream>>>(h1, h2r, Wout, dinv1, ts2);
    k_gcn_out<<<NN, 64, 0, stream>>>(ts2, rp, cols, dinv1, bout, Fcur, out, step);
  }
}

// Round 4
// 945.457 us; speedup vs baseline: 1.4820x; 1.2323x over previous
//
#include <hip/hip_runtime.h>
#include <math.h>

#define NN 4096
#define EE 65536
#define H 128
#define NF 4
#define MNODE 8
#define MEDGE 4
#define NT 2

// ---------------- CSR build ----------------
__global__ void k_count(const int* __restrict__ dst, int* __restrict__ cnt) {
  int e = blockIdx.x * 256 + threadIdx.x;
  if (e < EE) atomicAdd(&cnt[dst[e]], 1);
}

__global__ void k_scan(const int* __restrict__ cnt, int* __restrict__ rp) {
  __shared__ int sh[1024];
  int t = threadIdx.x;
  int v0 = cnt[4*t], v1 = cnt[4*t+1], v2 = cnt[4*t+2], v3 = cnt[4*t+3];
  int p1 = v0, p2 = v0 + v1, p3 = p2 + v2, tot = p3 + v3;
  sh[t] = tot; __syncthreads();
  for (int off = 1; off < 1024; off <<= 1) {
    int add = (t >= off) ? sh[t-off] : 0;
    __syncthreads();
    sh[t] += add;
    __syncthreads();
  }
  int base = sh[t] - tot;
  rp[4*t] = base; rp[4*t+1] = base + p1; rp[4*t+2] = base + p2; rp[4*t+3] = base + p3;
  if (t == 1023) rp[NN] = sh[t];
}

__global__ void k_fill(const int* __restrict__ ei, int* __restrict__ cursor, int* __restrict__ cols) {
  int e = blockIdx.x * 256 + threadIdx.x;
  if (e < EE) {
    int d = ei[EE + e], s = ei[e];
    int pos = atomicAdd(&cursor[d], 1);
    cols[pos] = s;
  }
}

__global__ void k_dinv0(const int* __restrict__ cnt, float* __restrict__ d2, float* __restrict__ d1) {
  int i = blockIdx.x * 256 + threadIdx.x;
  if (i < NN) {
    float c = (float)cnt[i];
    d2[i] = 1.f / sqrtf(c + 2.f);
    d1[i] = 1.f / sqrtf(c + 1.f);
  }
}

__global__ void k_pwnorm(const float* __restrict__ pw, float* __restrict__ pwn) {
  int l = blockIdx.x, t = threadIdx.x; // 64 threads
  float a = pw[l*H + t], b = pw[l*H + 64 + t];
  float s = a*a + b*b;
  for (int off = 32; off > 0; off >>= 1) s += __shfl_down(s, off);
  if (t == 0) pwn[l] = sqrtf(s);
}

__global__ void k_segS(const int* __restrict__ dst, const float* __restrict__ me, float* __restrict__ S) {
  int e = blockIdx.x * 256 + threadIdx.x;
  if (e < EE) {
    int d = dst[e];
#pragma unroll
    for (int m = 0; m < MEDGE; m++) atomicAdd(&S[d*MEDGE + m], me[e*MEDGE + m]);
  }
}

// ---------------- node_attr & matmuls ----------------
__global__ void k_na(const float* __restrict__ F, const float* __restrict__ mn,
                     const float* __restrict__ h, float* __restrict__ na) {
  int idx = blockIdx.x * 256 + threadIdx.x;
  if (idx >= NN * 140) return;
  int row = idx / 140, c = idx - row * 140;
  float v;
  if (c < NF) v = F[row*NF + c];
  else if (c < NF + MNODE) v = mn[row*MNODE + (c - NF)];
  else v = h[row*H + (c - NF - MNODE)];
  na[idx] = v;
}

// C[row,0:128] = A[row,:K] @ B[:K,0:128]  (B row-stride 128); optional row scale by dinv
__global__ void k_mm_rb(const float* __restrict__ A, int lda, const float* __restrict__ B,
                        float* __restrict__ C, int K, const float* __restrict__ dinv) {
  __shared__ float as[160];
  int row = blockIdx.x, t = threadIdx.x;
  float acc = 0.f;
  for (int k0 = 0; k0 < K; k0 += H) {
    int m = (K - k0 < H) ? (K - k0) : H;
    if (t < m) as[t] = A[(size_t)row*lda + k0 + t];
    __syncthreads();
    for (int kk = 0; kk < m; kk++) acc += as[kk] * B[(k0 + kk)*H + t];
    __syncthreads();
  }
  if (dinv) acc *= dinv[row];
  C[(size_t)row*H + t] = acc;
}

// SpMM over CSR rows; if dinv!=null apply GCN epilogue: dinv_i*(acc + fill*ts_i) + bias (+relu)
__global__ void k_spmm_fused(const float* __restrict__ ts, const int* __restrict__ rp,
                             const int* __restrict__ cols, const float* __restrict__ dinv,
                             float fill, const float* __restrict__ bias, int relu,
                             float* __restrict__ out) {
  int i = blockIdx.x, t = threadIdx.x;
  float acc = 0.f;
  int beg = rp[i], end = rp[i+1];
  for (int e = beg; e < end; e++) acc += ts[(size_t)cols[e]*H + t];
  float v;
  if (dinv) {
    v = dinv[i] * (acc + fill * ts[(size_t)i*H + t]) + bias[t];
    if (relu) v = fmaxf(v, 0.f);
  } else v = acc;
  out[(size_t)i*H + t] = v;
}

__global__ void k_h1(const float* __restrict__ P, const float* __restrict__ bm,
                     const float* __restrict__ AQ, const float* __restrict__ S,
                     const float* __restrict__ WmB, const int* __restrict__ cnt,
                     float* __restrict__ h1) {
  int i = blockIdx.x, t = threadIdx.x;
  float v = (float)cnt[i] * (P[(size_t)i*H + t] + bm[t]) + AQ[(size_t)i*H + t];
#pragma unroll
  for (int m = 0; m < MEDGE; m++) v += S[i*MEDGE + m] * WmB[m*H + t];
  h1[(size_t)i*H + t] = fmaxf(v, 0.f);
}

// ---------------- top-k pooling ----------------
// score + sortable key build + rank init, fused.
// key = (sortable(score) << 12) | (4095 - i)  -- matches jax.lax.top_k tie-break (lower idx wins)
__global__ void k_score(const float* __restrict__ x, const float* __restrict__ pw,
                        const float* __restrict__ pwn, float* __restrict__ score,
                        unsigned long long* __restrict__ keys, int* __restrict__ rank) {
  int row = blockIdx.x, t = threadIdx.x; // 64 threads
  float s = x[(size_t)row*H + t]*pw[t] + x[(size_t)row*H + 64 + t]*pw[64 + t];
  for (int off = 32; off > 0; off >>= 1) s += __shfl_down(s, off);
  if (t == 0) {
    float sc = tanhf(s / pwn[0]);
    score[row] = sc;
    float s2 = sc + 0.0f;                   // canonicalize -0.0 -> +0.0
    unsigned u = __float_as_uint(s2);
    u ^= (unsigned)(((int)u >> 31)) | 0x80000000u;  // ascending-sortable
    keys[row] = ((unsigned long long)u << 12) | (unsigned)(4095 - row);
    rank[row] = 0;
  }
}

// 2-D tiled rank count: block (bi,bj) compares i-stripe [bi*256..) vs j-tile [bj*256..).
__global__ void k_count_rank(const unsigned long long* __restrict__ keys, int n,
                             int* __restrict__ rank) {
  __shared__ unsigned long long sk[256];
  int t = threadIdx.x;
  int j = blockIdx.y * 256 + t;
  sk[t] = (j < n) ? keys[j] : 0ull;
  __syncthreads();
  int i = blockIdx.x * 256 + t;
  if (i >= n) return;
  unsigned long long ki = keys[i];
  int r = 0;
#pragma unroll 8
  for (int jj = 0; jj < 256; jj++) r += (sk[jj] > ki) ? 1 : 0;
  if (r) atomicAdd(&rank[i], r);
}

__global__ void k_select(const float* __restrict__ score, const int* __restrict__ rank,
                         int n, int k, int* __restrict__ perm, float* __restrict__ sv) {
  int i = blockIdx.x * 256 + threadIdx.x;
  if (i < n) {
    int r = rank[i];
    if (r < k) { perm[r] = i; sv[r] = score[i]; }
  }
}

__global__ void k_poolx(const float* __restrict__ x, const int* __restrict__ perm,
                        const float* __restrict__ sv, float* __restrict__ xp) {
  int r = blockIdx.x, t = threadIdx.x;
  xp[(size_t)r*H + t] = x[(size_t)perm[r]*H + t] * sv[r];
}

// A_820[r,c] = (A1@A1)[perm_r, perm_c], diag zeroed; A1 = offdiag(A0)+I via CSR
__global__ void k_a820(const int* __restrict__ rp, const int* __restrict__ cols,
                       const int* __restrict__ perm, float* __restrict__ A820) {
  __shared__ float acc[NN];
  int r = blockIdx.x, t = threadIdx.x;
  for (int i = t; i < NN; i += 256) acc[i] = 0.f;
  __syncthreads();
  int pi = perm[r];
  int beg = rp[pi], end = rp[pi+1];
  // k = pi term: + A1[pi,:]
  for (int e = beg + t; e < end; e += 256) { int c = cols[e]; if (c != pi) atomicAdd(&acc[c], 1.f); }
  if (t == 0) atomicAdd(&acc[pi], 1.f);
  // k != pi terms: for each off-diag edge instance (pi->c): + A1[c,:]
  for (int e0 = beg; e0 < end; e0++) {
    int c = cols[e0];
    if (c == pi) continue;
    int b2 = rp[c], e2 = rp[c+1];
    for (int e = b2 + t; e < e2; e += 256) { int c2 = cols[e]; if (c2 != c) atomicAdd(&acc[c2], 1.f); }
    if (t == 0) atomicAdd(&acc[c], 1.f);
  }
  __syncthreads();
  for (int cc = t; cc < 820; cc += 256)
    A820[(size_t)r*820 + cc] = (cc == r) ? 0.f : acc[perm[cc]];
}

// column pre-gather: AP[kk][c] = A[kk][perm[c]]   (n x knext, row-major)
__global__ void k_gathercols(const float* __restrict__ A, int n, const int* __restrict__ perm,
                             int knext, float* __restrict__ AP) {
  int idx = blockIdx.x * 256 + threadIdx.x;
  int total = n * knext;
  if (idx >= total) return;
  int kk = idx / knext, c = idx - kk * knext;
  AP[idx] = A[(size_t)kk * n + perm[c]];
}

// dense level augment+pool via pre-gathered columns:
// out[r][c] = sum_kk A[pr][kk] * AP[kk][c] + 2*AP[pr][c]   (r!=c), 0 on diag
__global__ void k_augpool2(const float* __restrict__ A, const float* __restrict__ AP,
                           int n, const int* __restrict__ perm, int knext,
                           float* __restrict__ out) {
  __shared__ float rowb[832];
  int r = blockIdx.x, t = threadIdx.x;
  int pr = perm[r];
  for (int i = t; i < n; i += 256) rowb[i] = A[(size_t)pr*n + i];
  __syncthreads();
  for (int c = t; c < knext; c += 256) {
    float dot = 0.f;
#pragma unroll 8
    for (int kk = 0; kk < n; kk++) dot += rowb[kk] * AP[(size_t)kk*knext + c];
    out[(size_t)r*knext + c] = (c == r) ? 0.f : (dot + 2.f * AP[(size_t)pr*knext + c]);
  }
}

__global__ void k_rowsum_dinv(const float* __restrict__ A, int n, float fill, float* __restrict__ dv) {
  __shared__ float red[256];
  int r = blockIdx.x, t = threadIdx.x;
  float s = 0.f;
  for (int c = t; c < n; c += 256) s += A[(size_t)r*n + c];
  red[t] = s; __syncthreads();
  for (int off = 128; off > 0; off >>= 1) { if (t < off) red[t] += red[t+off]; __syncthreads(); }
  if (t == 0) dv[r] = 1.f / sqrtf(red[0] + fill);
}

// dense GCN apply: out[i,:] = dinv_i*(sum_k A[i,k]*ts[k,:] + fill*ts[i,:]) + b (+relu)
// Branch-free, barrier-free streaming dot: A-row reads are lane-uniform (L1 broadcast),
// ts reads are sequential coalesced streams -> loads pipeline deeply.
// (a==0 terms contribute exactly 0 for finite ts, so no sparsity branch needed.)
__global__ void k_dense_gcn(const float* __restrict__ A, int n, const float* __restrict__ ts,
                            const float* __restrict__ dinv, float fill, const float* __restrict__ bias,
                            int relu, float* __restrict__ out) {
  int i = blockIdx.x, t = threadIdx.x;
  const float* Ar = A + (size_t)i * n;
  float acc = 0.f;
  int kk = 0;
  int n4 = n & ~3;
#pragma unroll 2
  for (; kk < n4; kk += 4) {
    float a0 = Ar[kk+0], a1 = Ar[kk+1], a2 = Ar[kk+2], a3 = Ar[kk+3];
    float t0 = ts[(size_t)(kk+0)*H + t];
    float t1 = ts[(size_t)(kk+1)*H + t];
    float t2 = ts[(size_t)(kk+2)*H + t];
    float t3 = ts[(size_t)(kk+3)*H + t];
    acc += a0*t0; acc += a1*t1; acc += a2*t2; acc += a3*t3;
  }
  for (; kk < n; kk++) acc += Ar[kk] * ts[(size_t)kk*H + t];
  float v = dinv[i] * (acc + fill * ts[(size_t)i*H + t]) + bias[t];
  if (relu) v = fmaxf(v, 0.f);
  out[(size_t)i*H + t] = v;
}

__global__ void k_scatter_add(float* __restrict__ tmp, const int* __restrict__ perm,
                              const float* __restrict__ xc) {
  int r = blockIdx.x, t = threadIdx.x;
  tmp[(size_t)perm[r]*H + t] += xc[(size_t)r*H + t];
}

__global__ void k_relu(const float* __restrict__ x, float* __restrict__ y, int count) {
  int i = blockIdx.x * 256 + threadIdx.x;
  if (i < count) y[i] = fmaxf(x[i], 0.f);
}

// ts2[row,0:4] = dinv1_row * (cat([h1,h2r]) @ Wout)[row,:]
__global__ void k_outproj(const float* __restrict__ h1, const float* __restrict__ h2r,
                          const float* __restrict__ Wout, const float* __restrict__ dinv1,
                          float* __restrict__ ts2) {
  int row = blockIdx.x, t = threadIdx.x; // 64 threads
  float p0 = 0.f, p1 = 0.f, p2 = 0.f, p3 = 0.f;
#pragma unroll
  for (int half = 0; half < 2; half++) {
    float a = h1[(size_t)row*H + half*64 + t];
    const float* w = Wout + (half*64 + t)*4;
    p0 += a*w[0]; p1 += a*w[1]; p2 += a*w[2]; p3 += a*w[3];
    float b = h2r[(size_t)row*H + half*64 + t];
    const float* w2 = Wout + (128 + half*64 + t)*4;
    p0 += b*w2[0]; p1 += b*w2[1]; p2 += b*w2[2]; p3 += b*w2[3];
  }
  for (int off = 32; off > 0; off >>= 1) {
    p0 += __shfl_down(p0, off); p1 += __shfl_down(p1, off);
    p2 += __shfl_down(p2, off); p3 += __shfl_down(p3, off);
  }
  if (t == 0) {
    float d = dinv1[row];
    ts2[row*4+0] = d*p0; ts2[row*4+1] = d*p1; ts2[row*4+2] = d*p2; ts2[row*4+3] = d*p3;
  }
}

__global__ void k_gcn_out(const float* __restrict__ ts2, const int* __restrict__ rp,
                          const int* __restrict__ cols, const float* __restrict__ dinv1,
                          const float* __restrict__ bout, float* __restrict__ Fcur,
                          float* __restrict__ dout, int tstep) {
  int i = blockIdx.x, t = threadIdx.x; // 64 threads
  int f = t & 3;
  float acc = 0.f;
  int beg = rp[i], end = rp[i+1];
  for (int e = beg + (t >> 2); e < end; e += 16) acc += ts2[cols[e]*4 + f];
  for (int off = 32; off >= 4; off >>= 1) acc += __shfl_down(acc, off);
  if (t < 4) {
    float v = dinv1[i] * (acc + ts2[i*4 + f]) + bout[f];
    Fcur[i*4 + f] = v;
    dout[i*(NT*NF) + tstep*NF + f] = v;
  }
}

extern "C" void kernel_launch(void* const* d_in, const int* in_sizes, int n_in,
                              void* d_out, int out_size, void* d_ws, size_t ws_size,
                              hipStream_t stream) {
  const float* F0        = (const float*)d_in[0];
  const float* mesh_node = (const float*)d_in[1];
  const float* mesh_edge = (const float*)d_in[2];
  const float* Wm        = (const float*)d_in[3];
  const float* bm        = (const float*)d_in[4];
  const float* Wd0       = (const float*)d_in[5];
  const float* bd0       = (const float*)d_in[6];
  const float* Wd        = (const float*)d_in[7];
  const float* bd        = (const float*)d_in[8];
  const float* pool_w    = (const float*)d_in[9];
  const float* Wu        = (const float*)d_in[10];
  const float* bu        = (const float*)d_in[11];
  const float* Wout      = (const float*)d_in[12];
  const float* bout      = (const float*)d_in[13];
  const int*   ei        = (const int*)d_in[14];
  float* out = (float*)d_out;

  char* p = (char*)d_ws;
  auto carve = [&](size_t bytes) -> char* {
    char* r = p;
    p += (bytes + 255) & ~(size_t)255;
    return r;
  };
  int*   cnt    = (int*)carve((size_t)NN*4);
  int*   rp     = (int*)carve((size_t)(NN+1)*4);
  int*   cursor = (int*)carve((size_t)NN*4);
  int*   cols   = (int*)carve((size_t)EE*4);
  int*   permb  = (int*)carve((size_t)5*832*4);
  float* svb    = (float*)carve((size_t)5*832*4);
  float* dinv2  = (float*)carve((size_t)NN*4);
  float* dinv1  = (float*)carve((size_t)NN*4);
  float* pwn    = (float*)carve(8*4);
  float* S      = (float*)carve((size_t)NN*MEDGE*4);
  float* na     = (float*)carve((size_t)NN*140*4);
  float* P      = (float*)carve((size_t)NN*H*4);
  float* Q      = (float*)carve((size_t)NN*H*4);
  float* h1     = (float*)carve((size_t)NN*H*4);
  float* hbuf   = (float*)carve((size_t)NN*H*4);
  float* h2r    = (float*)carve((size_t)NN*H*4);
  float* tsb    = (float*)carve((size_t)NN*H*4);
  float* tmp    = (float*)carve((size_t)NN*H*4);   // AQ scratch; also AP scratch in down path
  float* x0     = (float*)carve((size_t)NN*H*4);
  float* x1     = (float*)carve((size_t)820*H*4);
  float* x2     = (float*)carve((size_t)164*H*4);
  float* x3     = (float*)carve((size_t)33*H*4);
  float* x4     = (float*)carve((size_t)7*H*4);
  float* xp     = (float*)carve((size_t)820*H*4);
  float* xcur   = (float*)carve((size_t)820*H*4);
  float* score  = (float*)carve((size_t)NN*4);
  unsigned long long* keysb = (unsigned long long*)carve((size_t)NN*8);
  int*   rankb  = (int*)carve((size_t)NN*4);
  float* A820   = (float*)carve((size_t)820*820*4);
  float* A164   = (float*)carve((size_t)164*164*4);
  float* A33    = (float*)carve((size_t)33*33*4);
  float* A7     = (float*)carve((size_t)7*7*4);
  float* A2b    = (float*)carve((size_t)2*2*4);
  float* dv820  = (float*)carve(820*4);
  float* dv164  = (float*)carve(164*4);
  float* dv33   = (float*)carve(33*4);
  float* dv7    = (float*)carve(7*4);
  float* dv2    = (float*)carve(2*4);
  float* ts2    = (float*)carve((size_t)NN*NF*4);
  float* Fcur   = (float*)carve((size_t)NN*NF*4);

  // AP aliases tmp: tmp is dead between k_h1 (consumes AQ) and the up-path memcpy.
  // Max AP size = 820*164*4 = 537,920 B << NN*H*4 = 2 MB.
  float* AP = tmp;

  const int KLh[5]  = {820, 164, 33, 7, 2};
  const int szs[5]  = {4096, 820, 164, 33, 7};
  float* Adense[5] = {A820, A164, A33, A7, A2b};
  float* dvl[5]    = {dv820, dv164, dv33, dv7, dv2};
  float* xsv[5]    = {x0, x1, x2, x3, x4};
  int* perml[5]; float* svl[5];
  for (int l = 0; l < 5; l++) { perml[l] = permb + l*832; svl[l] = svb + l*832; }

  // ---- setup (once per launch) ----
  hipMemsetAsync(cnt, 0, (size_t)NN*4, stream);
  hipMemsetAsync(S, 0, (size_t)NN*MEDGE*4, stream);
  hipMemsetAsync(hbuf, 0, (size_t)NN*H*4, stream);
  k_count<<<EE/256, 256, 0, stream>>>(ei + EE, cnt);
  k_scan<<<1, 1024, 0, stream>>>(cnt, rp);
  hipMemcpyAsync(cursor, rp, (size_t)NN*4, hipMemcpyDeviceToDevice, stream);
  k_fill<<<EE/256, 256, 0, stream>>>(ei, cursor, cols);
  k_dinv0<<<NN/256, 256, 0, stream>>>(cnt, dinv2, dinv1);
  k_pwnorm<<<5, 64, 0, stream>>>(pool_w, pwn);
  k_segS<<<EE/256, 256, 0, stream>>>(ei + EE, mesh_edge, S);
  hipMemcpyAsync(Fcur, F0, (size_t)NN*NF*4, hipMemcpyDeviceToDevice, stream);

  for (int step = 0; step < NT; step++) {
    // edge MLP (factored) -> h1
    k_na<<<(NN*140 + 255)/256, 256, 0, stream>>>(Fcur, mesh_node, hbuf, na);
    k_mm_rb<<<NN, 128, 0, stream>>>(na, 140, Wm, P, 140, nullptr);
    k_mm_rb<<<NN, 128, 0, stream>>>(na, 140, Wm + 140*H, Q, 140, nullptr);
    k_spmm_fused<<<NN, 128, 0, stream>>>(Q, rp, cols, nullptr, 0.f, nullptr, 0, tmp); // AQ
    k_h1<<<NN, 128, 0, stream>>>(P, bm, tmp, S, Wm + 280*H, cnt, h1);

    // down GCN0 at 4096 (fill=2), relu
    k_mm_rb<<<NN, 128, 0, stream>>>(h1, H, Wd0, tsb, H, dinv2);
    k_spmm_fused<<<NN, 128, 0, stream>>>(tsb, rp, cols, dinv2, 2.f, bd0, 1, x0);

    // down path
    for (int i = 0; i < 5; i++) {
      int n_prev = szs[i], k = KLh[i];
      int gb = (n_prev + 255) / 256;
      k_score<<<n_prev, 64, 0, stream>>>(xsv[i], pool_w + i*H, pwn + i, score, keysb, rankb);
      k_count_rank<<<dim3(gb, gb), 256, 0, stream>>>(keysb, n_prev, rankb);
      k_select<<<gb, 256, 0, stream>>>(score, rankb, n_prev, k, perml[i], svl[i]);
      k_poolx<<<k, 128, 0, stream>>>(xsv[i], perml[i], svl[i], xp);
      if (i == 0) {
        k_a820<<<820, 256, 0, stream>>>(rp, cols, perml[0], Adense[0]);
      } else {
        int tot = n_prev * k;
        k_gathercols<<<(tot + 255)/256, 256, 0, stream>>>(Adense[i-1], n_prev, perml[i], k, AP);
        k_augpool2<<<k, 256, 0, stream>>>(Adense[i-1], AP, n_prev, perml[i], k, Adense[i]);
      }
      k_rowsum_dinv<<<k, 256, 0, stream>>>(Adense[i], k, 2.f, dvl[i]);
      k_mm_rb<<<k, 128, 0, stream>>>(xp, H, Wd + i*H*H, tsb, H, dvl[i]);
      float* outx = (i < 4) ? xsv[i+1] : xcur;
      k_dense_gcn<<<k, 128, 0, stream>>>(Adense[i], k, tsb, dvl[i], 2.f, bd + i*H, 1, outx);
    }

    // up path
    for (int i = 0; i < 5; i++) {
      int j = 4 - i;
      int n = szs[j], kk = KLh[j];
      hipMemcpyAsync(tmp, xsv[j], (size_t)n*H*4, hipMemcpyDeviceToDevice, stream);
      k_scatter_add<<<kk, 128, 0, stream>>>(tmp, perml[j], xcur);
      if (j > 0) {
        k_mm_rb<<<n, 128, 0, stream>>>(tmp, H, Wu + i*H*H, tsb, H, dvl[j-1]);
        k_dense_gcn<<<n, 128, 0, stream>>>(Adense[j-1], n, tsb, dvl[j-1], 2.f, bu + i*H,
                                           (i < 4) ? 1 : 0, xcur);
      } else {
        k_mm_rb<<<n, 128, 0, stream>>>(tmp, H, Wu + i*H*H, tsb, H, dinv2);
        k_spmm_fused<<<n, 128, 0, stream>>>(tsb, rp, cols, dinv2, 2.f, bu + i*H, 0, hbuf);
      }
    }

    // output GCN (fill=1)
    k_relu<<<(NN*H + 255)/256, 256, 0, stream>>>(hbuf, h2r, NN*H);
    k_outproj<<<NN, 64, 0, stream>>>(h1, h2r, Wout, dinv1, ts2);
    k_gcn_out<<<NN, 64, 0, stream>>>(ts2, rp, cols, dinv1, bout, Fcur, out, step);
  }
}

// Round 5
// 800.491 us; speedup vs baseline: 1.7503x; 1.1811x over previous
//
#include <hip/hip_runtime.h>
#include <math.h>

#define NN 4096
#define EE 65536
#define H 128
#define NF 4
#define MNODE 8
#define MEDGE 4
#define NT 2

// ---------------- CSR build ----------------
__global__ void k_count(const int* __restrict__ dst, int* __restrict__ cnt) {
  int e = blockIdx.x * 256 + threadIdx.x;
  if (e < EE) atomicAdd(&cnt[dst[e]], 1);
}

__global__ void k_scan(const int* __restrict__ cnt, int* __restrict__ rp) {
  __shared__ int sh[1024];
  int t = threadIdx.x;
  int v0 = cnt[4*t], v1 = cnt[4*t+1], v2 = cnt[4*t+2], v3 = cnt[4*t+3];
  int p1 = v0, p2 = v0 + v1, p3 = p2 + v2, tot = p3 + v3;
  sh[t] = tot; __syncthreads();
  for (int off = 1; off < 1024; off <<= 1) {
    int add = (t >= off) ? sh[t-off] : 0;
    __syncthreads();
    sh[t] += add;
    __syncthreads();
  }
  int base = sh[t] - tot;
  rp[4*t] = base; rp[4*t+1] = base + p1; rp[4*t+2] = base + p2; rp[4*t+3] = base + p3;
  if (t == 1023) rp[NN] = sh[t];
}

__global__ void k_fill(const int* __restrict__ ei, int* __restrict__ cursor, int* __restrict__ cols) {
  int e = blockIdx.x * 256 + threadIdx.x;
  if (e < EE) {
    int d = ei[EE + e], s = ei[e];
    int pos = atomicAdd(&cursor[d], 1);
    cols[pos] = s;
  }
}

__global__ void k_dinv0(const int* __restrict__ cnt, float* __restrict__ d2, float* __restrict__ d1) {
  int i = blockIdx.x * 256 + threadIdx.x;
  if (i < NN) {
    float c = (float)cnt[i];
    d2[i] = 1.f / sqrtf(c + 2.f);
    d1[i] = 1.f / sqrtf(c + 1.f);
  }
}

__global__ void k_pwnorm(const float* __restrict__ pw, float* __restrict__ pwn) {
  int l = blockIdx.x, t = threadIdx.x; // 64 threads
  float a = pw[l*H + t], b = pw[l*H + 64 + t];
  float s = a*a + b*b;
  for (int off = 32; off > 0; off >>= 1) s += __shfl_down(s, off);
  if (t == 0) pwn[l] = sqrtf(s);
}

__global__ void k_segS(const int* __restrict__ dst, const float* __restrict__ me, float* __restrict__ S) {
  int e = blockIdx.x * 256 + threadIdx.x;
  if (e < EE) {
    int d = dst[e];
#pragma unroll
    for (int m = 0; m < MEDGE; m++) atomicAdd(&S[d*MEDGE + m], me[e*MEDGE + m]);
  }
}

// ---------------- fused edge-MLP input projections ----------------
// Stages cat([F,mn,h])[row] once in LDS; computes P = na@Wm[0:140], Q = na@Wm[140:280].
__global__ void k_mm_cat(const float* __restrict__ F, const float* __restrict__ mn,
                         const float* __restrict__ h, const float* __restrict__ Wm,
                         float* __restrict__ P, float* __restrict__ Q) {
  __shared__ float as[140];
  int row = blockIdx.x, t = threadIdx.x; // 128 threads
  for (int c = t; c < 140; c += 128) {
    float v;
    if (c < NF) v = F[row*NF + c];
    else if (c < NF + MNODE) v = mn[row*MNODE + (c - NF)];
    else v = h[(size_t)row*H + (c - NF - MNODE)];
    as[c] = v;
  }
  __syncthreads();
  const float* BQ = Wm + 140*H;
  float ap = 0.f, aq = 0.f;
  for (int kk = 0; kk < 140; kk++) {
    float a = as[kk];
    ap += a * Wm[kk*H + t];
    aq += a * BQ[kk*H + t];
  }
  P[(size_t)row*H + t] = ap;
  Q[(size_t)row*H + t] = aq;
}

// ---------------- fused: spmm(AQ) + h1 + mm_rb(h1,Wd0)*dinv2 ----------------
__global__ void k_spmm_h1_mm(const float* __restrict__ Q, const int* __restrict__ rp,
                             const int* __restrict__ cols, const float* __restrict__ Pm,
                             const float* __restrict__ bm, const float* __restrict__ S,
                             const float* __restrict__ WmB, const int* __restrict__ cnt,
                             const float* __restrict__ Wd0, const float* __restrict__ dinv2,
                             float* __restrict__ h1, float* __restrict__ tsb) {
  __shared__ float hs[128];
  int i = blockIdx.x, t = threadIdx.x;
  float acc = 0.f;
  int beg = rp[i], end = rp[i+1];
  for (int e = beg; e < end; e++) acc += Q[(size_t)cols[e]*H + t];
  float v = (float)cnt[i] * (Pm[(size_t)i*H + t] + bm[t]) + acc;
#pragma unroll
  for (int m = 0; m < MEDGE; m++) v += S[i*MEDGE + m] * WmB[m*H + t];
  v = fmaxf(v, 0.f);
  h1[(size_t)i*H + t] = v;
  hs[t] = v;
  __syncthreads();
  float a2 = 0.f;
  for (int kk = 0; kk < H; kk++) a2 += hs[kk] * Wd0[kk*H + t];
  tsb[(size_t)i*H + t] = a2 * dinv2[i];
}

// ---------------- generic row-block matmul ----------------
__global__ void k_mm_rb(const float* __restrict__ A, int lda, const float* __restrict__ B,
                        float* __restrict__ C, int K, const float* __restrict__ dinv) {
  __shared__ float as[160];
  int row = blockIdx.x, t = threadIdx.x;
  float acc = 0.f;
  for (int k0 = 0; k0 < K; k0 += H) {
    int m = (K - k0 < H) ? (K - k0) : H;
    if (t < m) as[t] = A[(size_t)row*lda + k0 + t];
    __syncthreads();
    for (int kk = 0; kk < m; kk++) acc += as[kk] * B[(k0 + kk)*H + t];
    __syncthreads();
  }
  if (dinv) acc *= dinv[row];
  C[(size_t)row*H + t] = acc;
}

// SpMM over CSR rows; if dinv!=null apply GCN epilogue
__global__ void k_spmm_fused(const float* __restrict__ ts, const int* __restrict__ rp,
                             const int* __restrict__ cols, const float* __restrict__ dinv,
                             float fill, const float* __restrict__ bias, int relu,
                             float* __restrict__ out) {
  int i = blockIdx.x, t = threadIdx.x;
  float acc = 0.f;
  int beg = rp[i], end = rp[i+1];
  for (int e = beg; e < end; e++) acc += ts[(size_t)cols[e]*H + t];
  float v;
  if (dinv) {
    v = dinv[i] * (acc + fill * ts[(size_t)i*H + t]) + bias[t];
    if (relu) v = fmaxf(v, 0.f);
  } else v = acc;
  out[(size_t)i*H + t] = v;
}

// ---------------- top-k pooling ----------------
__global__ void k_score(const float* __restrict__ x, const float* __restrict__ pw,
                        const float* __restrict__ pwn, float* __restrict__ score,
                        unsigned long long* __restrict__ keys, int* __restrict__ rank) {
  int row = blockIdx.x, t = threadIdx.x; // 64 threads
  float s = x[(size_t)row*H + t]*pw[t] + x[(size_t)row*H + 64 + t]*pw[64 + t];
  for (int off = 32; off > 0; off >>= 1) s += __shfl_down(s, off);
  if (t == 0) {
    float sc = tanhf(s / pwn[0]);
    score[row] = sc;
    float s2 = sc + 0.0f;
    unsigned u = __float_as_uint(s2);
    u ^= (unsigned)(((int)u >> 31)) | 0x80000000u;
    keys[row] = ((unsigned long long)u << 12) | (unsigned)(4095 - row);
    rank[row] = 0;
  }
}

__global__ void k_count_rank(const unsigned long long* __restrict__ keys, int n,
                             int* __restrict__ rank) {
  __shared__ unsigned long long sk[256];
  int t = threadIdx.x;
  int j = blockIdx.y * 256 + t;
  sk[t] = (j < n) ? keys[j] : 0ull;
  __syncthreads();
  int i = blockIdx.x * 256 + t;
  if (i >= n) return;
  unsigned long long ki = keys[i];
  int r = 0;
#pragma unroll 8
  for (int jj = 0; jj < 256; jj++) r += (sk[jj] > ki) ? 1 : 0;
  if (r) atomicAdd(&rank[i], r);
}

// select + write inverse map (inv[i] = rank; row i -> pooled row inv[i] iff inv[i] < k)
__global__ void k_select(const float* __restrict__ score, const int* __restrict__ rank,
                         int n, int k, int* __restrict__ perm, float* __restrict__ sv,
                         int* __restrict__ inv) {
  int i = blockIdx.x * 256 + threadIdx.x;
  if (i < n) {
    int r = rank[i];
    inv[i] = r;
    if (r < k) { perm[r] = i; sv[r] = score[i]; }
  }
}

__global__ void k_poolx(const float* __restrict__ x, const int* __restrict__ perm,
                        const float* __restrict__ sv, float* __restrict__ xp) {
  int r = blockIdx.x, t = threadIdx.x;
  xp[(size_t)r*H + t] = x[(size_t)perm[r]*H + t] * sv[r];
}

// single-block fused rank+select+poolx for n <= 256
__global__ void k_pool_small(const float* __restrict__ score, const unsigned long long* __restrict__ keys,
                             const float* __restrict__ x, int n, int k,
                             int* __restrict__ perm, float* __restrict__ sv,
                             int* __restrict__ inv, float* __restrict__ xp) {
  __shared__ unsigned long long ks[256];
  __shared__ int permS[40];
  __shared__ float svS[40];
  int t = threadIdx.x; // 256 threads
  ks[t] = (t < n) ? keys[t] : 0ull;
  __syncthreads();
  if (t < n) {
    unsigned long long ki = ks[t];
    int r = 0;
    for (int j = 0; j < n; j++) r += (ks[j] > ki) ? 1 : 0;
    inv[t] = r;
    if (r < k) {
      float sc = score[t];
      permS[r] = t; svS[r] = sc;
      perm[r] = t; sv[r] = sc;
    }
  }
  __syncthreads();
  for (int idx = t; idx < k*H; idx += 256) {
    int r = idx >> 7, c = idx & 127;
    xp[idx] = x[(size_t)permS[r]*H + c] * svS[r];
  }
}

// A_820 build with fused rowsum/dinv
__global__ void k_a820_f(const int* __restrict__ rp, const int* __restrict__ cols,
                         const int* __restrict__ perm, float* __restrict__ A820,
                         float* __restrict__ dv) {
  __shared__ float acc[NN];
  __shared__ float red[256];
  int r = blockIdx.x, t = threadIdx.x;
  for (int i = t; i < NN; i += 256) acc[i] = 0.f;
  __syncthreads();
  int pi = perm[r];
  int beg = rp[pi], end = rp[pi+1];
  for (int e = beg + t; e < end; e += 256) { int c = cols[e]; if (c != pi) atomicAdd(&acc[c], 1.f); }
  if (t == 0) atomicAdd(&acc[pi], 1.f);
  for (int e0 = beg; e0 < end; e0++) {
    int c = cols[e0];
    if (c == pi) continue;
    int b2 = rp[c], e2 = rp[c+1];
    for (int e = b2 + t; e < e2; e += 256) { int c2 = cols[e]; if (c2 != c) atomicAdd(&acc[c2], 1.f); }
    if (t == 0) atomicAdd(&acc[c], 1.f);
  }
  __syncthreads();
  float local = 0.f;
  for (int cc = t; cc < 820; cc += 256) {
    float val = (cc == r) ? 0.f : acc[perm[cc]];
    A820[(size_t)r*820 + cc] = val;
    local += val;
  }
  red[t] = local; __syncthreads();
  for (int off = 128; off > 0; off >>= 1) { if (t < off) red[t] += red[t+off]; __syncthreads(); }
  if (t == 0) dv[r] = 1.f / sqrtf(red[0] + 2.f);
}

// column pre-gather (level 1 only): AP[kk][c] = A[kk][perm[c]]
__global__ void k_gathercols(const float* __restrict__ A, int n, const int* __restrict__ perm,
                             int knext, float* __restrict__ AP) {
  int idx = blockIdx.x * 256 + threadIdx.x;
  int total = n * knext;
  if (idx >= total) return;
  int kk = idx / knext, c = idx - kk * knext;
  AP[idx] = A[(size_t)kk * n + perm[c]];
}

// level-1 augment+pool with fused rowsum/dinv
__global__ void k_augpool2_f(const float* __restrict__ A, const float* __restrict__ AP,
                             int n, const int* __restrict__ perm, int knext,
                             float* __restrict__ out, float* __restrict__ dv) {
  __shared__ float rowb[832];
  __shared__ float red[256];
  int r = blockIdx.x, t = threadIdx.x;
  int pr = perm[r];
  for (int i = t; i < n; i += 256) rowb[i] = A[(size_t)pr*n + i];
  __syncthreads();
  float local = 0.f;
  for (int c = t; c < knext; c += 256) {
    float dot = 0.f;
#pragma unroll 8
    for (int kk = 0; kk < n; kk++) dot += rowb[kk] * AP[(size_t)kk*knext + c];
    float val = (c == r) ? 0.f : (dot + 2.f * AP[(size_t)pr*knext + c]);
    out[(size_t)r*knext + c] = val;
    local += val;
  }
  red[t] = local; __syncthreads();
  for (int off = 128; off > 0; off >>= 1) { if (t < off) red[t] += red[t+off]; __syncthreads(); }
  if (t == 0) dv[r] = 1.f / sqrtf(red[0] + 2.f);
}

// small-level augment+pool (n <= 256): 8 threads per output column, branch-free,
// fused rowsum/dinv. A is L2-resident at these sizes.
__global__ void k_augpool_small(const float* __restrict__ A, int n, const int* __restrict__ perm,
                                int knext, float* __restrict__ out, float* __restrict__ dv) {
  __shared__ float rowb[256];
  __shared__ float rsum;
  int r = blockIdx.x, t = threadIdx.x; // 256 threads
  int pr = perm[r];
  if (t < n) rowb[t] = A[(size_t)pr*n + t];
  if (t == 0) rsum = 0.f;
  __syncthreads();
  int g = t >> 3, lane = t & 7;
  for (int c = g; c < knext; c += 32) {
    int pc = perm[c];
    float part = 0.f;
    for (int kk = lane; kk < n; kk += 8) part += rowb[kk] * A[(size_t)kk*n + pc];
    part += __shfl_down(part, 4, 8);
    part += __shfl_down(part, 2, 8);
    part += __shfl_down(part, 1, 8);
    if (lane == 0) {
      float val = (c == r) ? 0.f : (part + 2.f * rowb[pc]);
      out[(size_t)r*knext + c] = val;
      atomicAdd(&rsum, val);
    }
  }
  __syncthreads();
  if (t == 0) dv[r] = 1.f / sqrtf(rsum + 2.f);
}

// dense GCN apply (branch-free streaming)
__global__ void k_dense_gcn(const float* __restrict__ A, int n, const float* __restrict__ ts,
                            const float* __restrict__ dinv, float fill, const float* __restrict__ bias,
                            int relu, float* __restrict__ out) {
  int i = blockIdx.x, t = threadIdx.x;
  const float* Ar = A + (size_t)i * n;
  float acc = 0.f;
  int kk = 0;
  int n4 = n & ~3;
#pragma unroll 2
  for (; kk < n4; kk += 4) {
    float a0 = Ar[kk+0], a1 = Ar[kk+1], a2 = Ar[kk+2], a3 = Ar[kk+3];
    float t0 = ts[(size_t)(kk+0)*H + t];
    float t1 = ts[(size_t)(kk+1)*H + t];
    float t2 = ts[(size_t)(kk+2)*H + t];
    float t3 = ts[(size_t)(kk+3)*H + t];
    acc += a0*t0; acc += a1*t1; acc += a2*t2; acc += a3*t3;
  }
  for (; kk < n; kk++) acc += Ar[kk] * ts[(size_t)kk*H + t];
  float v = dinv[i] * (acc + fill * ts[(size_t)i*H + t]) + bias[t];
  if (relu) v = fmaxf(v, 0.f);
  out[(size_t)i*H + t] = v;
}

// up-path fused: (residual + inverse-perm scatter of xcur) @ W * dinv
__global__ void k_upproj(const float* __restrict__ xs, const int* __restrict__ inv,
                         const float* __restrict__ xcur, int kk,
                         const float* __restrict__ W, const float* __restrict__ dinv,
                         float* __restrict__ tsb) {
  __shared__ float hs[128];
  int i = blockIdx.x, t = threadIdx.x;
  int r = inv[i];
  float v = xs[(size_t)i*H + t];
  if (r < kk) v += xcur[(size_t)r*H + t];
  hs[t] = v;
  __syncthreads();
  float acc = 0.f;
  for (int k2 = 0; k2 < H; k2++) acc += hs[k2] * W[k2*H + t];
  tsb[(size_t)i*H + t] = acc * dinv[i];
}

// ts2[row,0:4] = dinv1_row * (cat([h1, relu(hbuf)]) @ Wout)[row,:]  (relu fused)
__global__ void k_outproj_r(const float* __restrict__ h1, const float* __restrict__ hbuf,
                            const float* __restrict__ Wout, const float* __restrict__ dinv1,
                            float* __restrict__ ts2) {
  int row = blockIdx.x, t = threadIdx.x; // 64 threads
  float p0 = 0.f, p1 = 0.f, p2 = 0.f, p3 = 0.f;
#pragma unroll
  for (int half = 0; half < 2; half++) {
    float a = h1[(size_t)row*H + half*64 + t];
    const float* w = Wout + (half*64 + t)*4;
    p0 += a*w[0]; p1 += a*w[1]; p2 += a*w[2]; p3 += a*w[3];
    float b = fmaxf(hbuf[(size_t)row*H + half*64 + t], 0.f);
    const float* w2 = Wout + (128 + half*64 + t)*4;
    p0 += b*w2[0]; p1 += b*w2[1]; p2 += b*w2[2]; p3 += b*w2[3];
  }
  for (int off = 32; off > 0; off >>= 1) {
    p0 += __shfl_down(p0, off); p1 += __shfl_down(p1, off);
    p2 += __shfl_down(p2, off); p3 += __shfl_down(p3, off);
  }
  if (t == 0) {
    float d = dinv1[row];
    ts2[row*4+0] = d*p0; ts2[row*4+1] = d*p1; ts2[row*4+2] = d*p2; ts2[row*4+3] = d*p3;
  }
}

__global__ void k_gcn_out(const float* __restrict__ ts2, const int* __restrict__ rp,
                          const int* __restrict__ cols, const float* __restrict__ dinv1,
                          const float* __restrict__ bout, float* __restrict__ Fcur,
                          float* __restrict__ dout, int tstep) {
  int i = blockIdx.x, t = threadIdx.x; // 64 threads
  int f = t & 3;
  float acc = 0.f;
  int beg = rp[i], end = rp[i+1];
  for (int e = beg + (t >> 2); e < end; e += 16) acc += ts2[cols[e]*4 + f];
  for (int off = 32; off >= 4; off >>= 1) acc += __shfl_down(acc, off);
  if (t < 4) {
    float v = dinv1[i] * (acc + ts2[i*4 + f]) + bout[f];
    Fcur[i*4 + f] = v;
    dout[i*(NT*NF) + tstep*NF + f] = v;
  }
}

extern "C" void kernel_launch(void* const* d_in, const int* in_sizes, int n_in,
                              void* d_out, int out_size, void* d_ws, size_t ws_size,
                              hipStream_t stream) {
  const float* F0        = (const float*)d_in[0];
  const float* mesh_node = (const float*)d_in[1];
  const float* mesh_edge = (const float*)d_in[2];
  const float* Wm        = (const float*)d_in[3];
  const float* bm        = (const float*)d_in[4];
  const float* Wd0       = (const float*)d_in[5];
  const float* bd0       = (const float*)d_in[6];
  const float* Wd        = (const float*)d_in[7];
  const float* bd        = (const float*)d_in[8];
  const float* pool_w    = (const float*)d_in[9];
  const float* Wu        = (const float*)d_in[10];
  const float* bu        = (const float*)d_in[11];
  const float* Wout      = (const float*)d_in[12];
  const float* bout      = (const float*)d_in[13];
  const int*   ei        = (const int*)d_in[14];
  float* out = (float*)d_out;

  char* p = (char*)d_ws;
  auto carve = [&](size_t bytes) -> char* {
    char* r = p;
    p += (bytes + 255) & ~(size_t)255;
    return r;
  };
  int*   cnt    = (int*)carve((size_t)NN*4);
  int*   rp     = (int*)carve((size_t)(NN+1)*4);
  int*   cursor = (int*)carve((size_t)NN*4);
  int*   cols   = (int*)carve((size_t)EE*4);
  int*   permb  = (int*)carve((size_t)5*832*4);
  float* svb    = (float*)carve((size_t)5*832*4);
  float* dinv2  = (float*)carve((size_t)NN*4);
  float* dinv1  = (float*)carve((size_t)NN*4);
  float* pwn    = (float*)carve(8*4);
  float* S      = (float*)carve((size_t)NN*MEDGE*4);
  int*   invb   = (int*)carve((size_t)5*NN*4);     // inverse-perm (rank) per level
  float* P      = (float*)carve((size_t)NN*H*4);
  float* Q      = (float*)carve((size_t)NN*H*4);
  float* h1     = (float*)carve((size_t)NN*H*4);
  float* hbuf   = (float*)carve((size_t)NN*H*4);
  float* tsb    = (float*)carve((size_t)NN*H*4);
  float* tmp    = (float*)carve((size_t)NN*H*4);   // AP scratch (down path level 1)
  float* x0     = (float*)carve((size_t)NN*H*4);
  float* x1     = (float*)carve((size_t)820*H*4);
  float* x2     = (float*)carve((size_t)164*H*4);
  float* x3     = (float*)carve((size_t)33*H*4);
  float* x4     = (float*)carve((size_t)7*H*4);
  float* xp     = (float*)carve((size_t)820*H*4);
  float* xcur   = (float*)carve((size_t)820*H*4);
  float* score  = (float*)carve((size_t)NN*4);
  unsigned long long* keysb = (unsigned long long*)carve((size_t)NN*8);
  int*   rankb  = (int*)carve((size_t)NN*4);
  float* A820   = (float*)carve((size_t)820*820*4);
  float* A164   = (float*)carve((size_t)164*164*4);
  float* A33    = (float*)carve((size_t)33*33*4);
  float* A7     = (float*)carve((size_t)7*7*4);
  float* A2b    = (float*)carve((size_t)2*2*4);
  float* dv820  = (float*)carve(820*4);
  float* dv164  = (float*)carve(164*4);
  float* dv33   = (float*)carve(33*4);
  float* dv7    = (float*)carve(7*4);
  float* dv2    = (float*)carve(2*4);
  float* ts2    = (float*)carve((size_t)NN*NF*4);
  float* Fcur   = (float*)carve((size_t)NN*NF*4);

  float* AP = tmp;

  const int KLh[5]  = {820, 164, 33, 7, 2};
  const int szs[5]  = {4096, 820, 164, 33, 7};
  float* Adense[5] = {A820, A164, A33, A7, A2b};
  float* dvl[5]    = {dv820, dv164, dv33, dv7, dv2};
  float* xsv[5]    = {x0, x1, x2, x3, x4};
  int* perml[5]; float* svl[5]; int* invl[5];
  for (int l = 0; l < 5; l++) {
    perml[l] = permb + l*832; svl[l] = svb + l*832; invl[l] = invb + l*NN;
  }

  // ---- setup (once per launch) ----
  hipMemsetAsync(cnt, 0, (size_t)NN*4, stream);
  hipMemsetAsync(S, 0, (size_t)NN*MEDGE*4, stream);
  hipMemsetAsync(hbuf, 0, (size_t)NN*H*4, stream);
  k_count<<<EE/256, 256, 0, stream>>>(ei + EE, cnt);
  k_scan<<<1, 1024, 0, stream>>>(cnt, rp);
  hipMemcpyAsync(cursor, rp, (size_t)NN*4, hipMemcpyDeviceToDevice, stream);
  k_fill<<<EE/256, 256, 0, stream>>>(ei, cursor, cols);
  k_dinv0<<<NN/256, 256, 0, stream>>>(cnt, dinv2, dinv1);
  k_pwnorm<<<5, 64, 0, stream>>>(pool_w, pwn);
  k_segS<<<EE/256, 256, 0, stream>>>(ei + EE, mesh_edge, S);
  hipMemcpyAsync(Fcur, F0, (size_t)NN*NF*4, hipMemcpyDeviceToDevice, stream);

  for (int step = 0; step < NT; step++) {
    // edge MLP (factored) -> h1 -> Wd0 projection, fused
    k_mm_cat<<<NN, 128, 0, stream>>>(Fcur, mesh_node, hbuf, Wm, P, Q);
    k_spmm_h1_mm<<<NN, 128, 0, stream>>>(Q, rp, cols, P, bm, S, Wm + 280*H, cnt,
                                         Wd0, dinv2, h1, tsb);
    k_spmm_fused<<<NN, 128, 0, stream>>>(tsb, rp, cols, dinv2, 2.f, bd0, 1, x0);

    // down path
    for (int i = 0; i < 5; i++) {
      int n_prev = szs[i], k = KLh[i];
      k_score<<<n_prev, 64, 0, stream>>>(xsv[i], pool_w + i*H, pwn + i, score, keysb, rankb);
      if (n_prev > 256) {
        int gb = (n_prev + 255) / 256;
        k_count_rank<<<dim3(gb, gb), 256, 0, stream>>>(keysb, n_prev, rankb);
        k_select<<<gb, 256, 0, stream>>>(score, rankb, n_prev, k, perml[i], svl[i], invl[i]);
        k_poolx<<<k, 128, 0, stream>>>(xsv[i], perml[i], svl[i], xp);
      } else {
        k_pool_small<<<1, 256, 0, stream>>>(score, keysb, xsv[i], n_prev, k,
                                            perml[i], svl[i], invl[i], xp);
      }
      if (i == 0) {
        k_a820_f<<<820, 256, 0, stream>>>(rp, cols, perml[0], A820, dv820);
      } else if (i == 1) {
        int tot = n_prev * k;
        k_gathercols<<<(tot + 255)/256, 256, 0, stream>>>(Adense[0], n_prev, perml[1], k, AP);
        k_augpool2_f<<<k, 256, 0, stream>>>(Adense[0], AP, n_prev, perml[1], k, Adense[1], dvl[1]);
      } else {
        k_augpool_small<<<k, 256, 0, stream>>>(Adense[i-1], n_prev, perml[i], k, Adense[i], dvl[i]);
      }
      k_mm_rb<<<k, 128, 0, stream>>>(xp, H, Wd + i*H*H, tsb, H, dvl[i]);
      float* outx = (i < 4) ? xsv[i+1] : xcur;
      k_dense_gcn<<<k, 128, 0, stream>>>(Adense[i], k, tsb, dvl[i], 2.f, bd + i*H, 1, outx);
    }

    // up path
    for (int i = 0; i < 5; i++) {
      int j = 4 - i;
      int n = szs[j], kk = KLh[j];
      k_upproj<<<n, 128, 0, stream>>>(xsv[j], invl[j], xcur, kk, Wu + i*H*H,
                                      (j > 0) ? dvl[j-1] : dinv2, tsb);
      if (j > 0) {
        k_dense_gcn<<<n, 128, 0, stream>>>(Adense[j-1], n, tsb, dvl[j-1], 2.f, bu + i*H,
                                           (i < 4) ? 1 : 0, xcur);
      } else {
        k_spmm_fused<<<n, 128, 0, stream>>>(tsb, rp, cols, dinv2, 2.f, bu + i*H, 0, hbuf);
      }
    }

    // output GCN (fill=1), relu fused into outproj
    k_outproj_r<<<NN, 64, 0, stream>>>(h1, hbuf, Wout, dinv1, ts2);
    k_gcn_out<<<NN, 64, 0, stream>>>(ts2, rp, cols, dinv1, bout, Fcur, out, step);
  }
}